// Round 3
// baseline (516.079 us; speedup 1.0000x reference)
//
#include <hip/hip_runtime.h>
#include <stdint.h>

#define B_ 4
#define T_ 2048
#define C_ 1024
#define H_ 128
#define NEG_BIG -3.0e38f

typedef __attribute__((ext_vector_type(8))) short short8;
typedef __attribute__((ext_vector_type(4))) float f32x4;
typedef __attribute__((ext_vector_type(4))) unsigned short ushort4v;
typedef __attribute__((ext_vector_type(8))) unsigned short ushort8v;

// cheap bf16 cast: round-half-up, <=0.5 ULP (validated R6-R9: absmax unchanged)
__device__ __forceinline__ unsigned short f2bf(float f) {
  union { float f; unsigned u; } cv; cv.f = f;
  return (unsigned short)((cv.u + 0x8000u) >> 16);
}

__device__ __forceinline__ float bf2f(unsigned short s) {
  union { unsigned u; float f; } cv; cv.u = ((unsigned)s) << 16;
  return cv.f;
}

// async global->LDS, 16 bytes per lane. LDS dest = wave-uniform base + lane*16.
__device__ __forceinline__ void gld16(const void* g, void* l) {
  __builtin_amdgcn_global_load_lds(
      (const __attribute__((address_space(1))) unsigned int*)g,
      (__attribute__((address_space(3))) unsigned int*)l, 16, 0, 0);
}

// Manual grid barrier (cooperative launch is NOT graph-capturable -> R2 fail).
// Monotone counter, target = 512 * k. Counter zeroed per-iteration by a
// hipMemsetAsync captured in the graph. __threadfence = agent-scope seq_cst
// fence -> L2 writeback/invalidate for cross-XCD visibility (G16).
// Co-residency by construction: 512 blocks @ launch_bounds(256,2), 75KB LDS.
__device__ __forceinline__ void gbar(unsigned int* cnt, unsigned int target) {
  __threadfence();           // release: this thread's writes -> device scope
  __syncthreads();
  if (threadIdx.x == 0) {
    __hip_atomic_fetch_add(cnt, 1u, __ATOMIC_ACQ_REL, __HIP_MEMORY_SCOPE_AGENT);
    unsigned int v;
    do {
      __builtin_amdgcn_s_sleep(2);
      v = __hip_atomic_load(cnt, __ATOMIC_ACQUIRE, __HIP_MEMORY_SCOPE_AGENT);
    } while (v < target);
  }
  __syncthreads();
  __threadfence();           // acquire: invalidate stale L1/L2 before reads
}

// scale = C^-0.5 = 1/32; folded with log2(e) for exp2-domain softmax
#define CSCALE 0.045084220027780106f

// ---------------------------------------------------------------------------
// R12: ONE kernel, 4 phases, 3 manual grid barriers (R11 theory, working
// mechanism). Phase bodies are byte-identical to the R1-passing kernels.
// Grid 512 x 256, __launch_bounds__(256,2): exactly 2 blocks/CU co-resident.
// LDS overlay: max(qkv 41KB, attn 75KB) = 75008 B; 2/CU = 150KB < 160KB.
// ---------------------------------------------------------------------------
__global__ __launch_bounds__(256, 2) void fused_head(
    const float* __restrict__ x, const float* __restrict__ Wq,
    const float* __restrict__ Wk, const float* __restrict__ Wv,
    unsigned short* __restrict__ WbT, unsigned short* __restrict__ Qb,
    unsigned short* __restrict__ Kb, unsigned short* __restrict__ VT,
    unsigned short* __restrict__ Opart, float* __restrict__ mpart,
    float* __restrict__ lpart, unsigned int* __restrict__ gsync,
    float* __restrict__ out) {
  __shared__ __align__(16) char smem[75008];

  const int tid = threadIdx.x;
  const int bid = blockIdx.x;
  const int wave = tid >> 6, lane = tid & 63;
  const int quad = lane >> 4, l15 = lane & 15;

  // ========================= phase 0: weight cast ==========================
  // WbT bf16 [384][1024] = (Wq|Wk|Wv)^T. 98304 ushort4 items.
  {
    const int i = bid * 256 + tid;
    if (i < 98304) {
      const int linear = i * 4;
      const int j = linear >> 10;
      const int k0 = linear & 1023;
      const float* W = (j < 128) ? Wq : (j < 256) ? Wk : Wv;
      const int h = j & 127;
      ushort4v p;
      p[0] = f2bf(W[(k0 + 0) * 128 + h]);
      p[1] = f2bf(W[(k0 + 1) * 128 + h]);
      p[2] = f2bf(W[(k0 + 2) * 128 + h]);
      p[3] = f2bf(W[(k0 + 3) * 128 + h]);
      *(ushort4v*)(WbT + linear) = p;
    }
  }
  gbar(gsync, 512);

  // ========================= phase 1: QKV projection =======================
  // 64M x 96N x 64K dbuf GEMM; rb = bid&127, cb = bid>>7 (x-sharing siblings
  // on same XCD). Wave 2x2 owns 32M x 48N. Q pre-scaled; V transposed.
  {
    unsigned short* const Asm = (unsigned short*)smem;            // 2 x 4096
    unsigned short* const Bsm = (unsigned short*)(smem + 16384);  // 2 x 6144

    const int rb = bid & 127, cb = bid >> 7;
    const int gm0 = rb * 64, gn0 = cb * 96;
    const int wm = wave >> 1, wn = wave & 1;
    const int srow = lane >> 3, sslot = lane & 7;
    const int axr = tid >> 3, axc = tid & 7;        // 32 rows x 8 chunks
    const float* gAx = x + (size_t)(gm0 + axr) * C_ + axc * 8;

    int aoff[2][2], boff[3][2];
#pragma unroll
    for (int mt = 0; mt < 2; ++mt) {
      const int r = wm * 32 + mt * 16 + l15;
#pragma unroll
      for (int ks = 0; ks < 2; ++ks)
        aoff[mt][ks] = r * 64 + (((ks * 4 + quad) ^ r) & 7) * 8;
    }
#pragma unroll
    for (int nt = 0; nt < 3; ++nt) {
      const int r = wn * 48 + nt * 16 + l15;
#pragma unroll
      for (int ks = 0; ks < 2; ++ks)
        boff[nt][ks] = r * 64 + (((ks * 4 + quad) ^ r) & 7) * 8;
    }

    f32x4 acc[2][3];
    const f32x4 zero4 = {0.f, 0.f, 0.f, 0.f};
#pragma unroll
    for (int mt = 0; mt < 2; ++mt)
#pragma unroll
      for (int nt = 0; nt < 3; ++nt) acc[mt][nt] = zero4;

#define QSTAGE_B(buf, kb_)                                                         \
    {                                                                              \
      const int ko = (kb_) * 64;                                                   \
      _Pragma("unroll")                                                            \
      for (int q = 0; q < 3; ++q) {                                                \
        const int row = wave * 24 + q * 8 + srow;                                  \
        gld16(WbT + (size_t)(gn0 + row) * C_ + ko + ((sslot ^ row) & 7) * 8,       \
              Bsm + (buf) * 6144 + (wave * 24 + q * 8) * 64);                      \
      }                                                                            \
    }

#define QLOAD_A(ko_)                                                               \
    _Pragma("unroll")                                                              \
    for (int q = 0; q < 2; ++q) {                                                  \
      av0[q] = *(const f32x4*)(gAx + (size_t)(q * 32) * C_ + (ko_));               \
      av1[q] = *(const f32x4*)(gAx + (size_t)(q * 32) * C_ + (ko_) + 4);           \
    }

#define QWRITE_A(buf)                                                              \
    _Pragma("unroll")                                                              \
    for (int q = 0; q < 2; ++q) {                                                  \
      const int row = axr + q * 32;                                                \
      short8 aw;                                                                   \
      _Pragma("unroll")                                                            \
      for (int e = 0; e < 4; ++e) {                                                \
        aw[e]     = (short)f2bf(av0[q][e]);                                        \
        aw[4 + e] = (short)f2bf(av1[q][e]);                                        \
      }                                                                            \
      *(short8*)(Asm + (buf) * 4096 + row * 64 + ((axc ^ row) & 7) * 8) = aw;      \
    }

    f32x4 av0[2], av1[2];
    QLOAD_A(0);
    QSTAGE_B(0, 0);
    QWRITE_A(0);

    for (int kb = 0; kb < 16; ++kb) {
      __syncthreads();
      const int cur = kb & 1, nxt = cur ^ 1;
      if (kb + 1 < 16) {
        QLOAD_A((kb + 1) * 64);
        QSTAGE_B(nxt, kb + 1);
      }
      const unsigned short* Ac = Asm + cur * 4096;
      const unsigned short* Bc = Bsm + cur * 6144;
#pragma unroll
      for (int ks = 0; ks < 2; ++ks) {
        short8 b0 = *(const short8*)(Bc + boff[0][ks]);
        short8 b1 = *(const short8*)(Bc + boff[1][ks]);
        short8 b2 = *(const short8*)(Bc + boff[2][ks]);
#pragma unroll
        for (int mt = 0; mt < 2; ++mt) {
          short8 a = *(const short8*)(Ac + aoff[mt][ks]);
          acc[mt][0] = __builtin_amdgcn_mfma_f32_16x16x32_bf16(a, b0, acc[mt][0], 0, 0, 0);
          acc[mt][1] = __builtin_amdgcn_mfma_f32_16x16x32_bf16(a, b1, acc[mt][1], 0, 0, 0);
          acc[mt][2] = __builtin_amdgcn_mfma_f32_16x16x32_bf16(a, b2, acc[mt][2], 0, 0, 0);
        }
      }
      if (kb + 1 < 16) QWRITE_A(nxt);
    }
#undef QSTAGE_B
#undef QLOAD_A
#undef QWRITE_A

    // epilogue: D[row=quad*4+r][col=l15] per 16x16 tile
#pragma unroll
    for (int mt = 0; mt < 2; ++mt) {
      const int row0 = gm0 + wm * 32 + mt * 16 + quad * 4;
#pragma unroll
      for (int nt = 0; nt < 3; ++nt) {
        const int colbase = gn0 + wn * 48 + nt * 16;
        const int col = colbase + l15;
        if (colbase < 128) {          // Q (pre-scaled)
#pragma unroll
          for (int r = 0; r < 4; ++r)
            Qb[(size_t)(row0 + r) * H_ + col] = f2bf(acc[mt][nt][r] * CSCALE);
        } else if (colbase < 256) {   // K
#pragma unroll
          for (int r = 0; r < 4; ++r)
            Kb[(size_t)(row0 + r) * H_ + (col - 128)] = f2bf(acc[mt][nt][r]);
        } else {                      // V, transposed
          const int h = col - 256;
          const int bidx = row0 >> 11;
          const int t0 = row0 & 2047;
          ushort4v pk;
          pk[0] = f2bf(acc[mt][nt][0]); pk[1] = f2bf(acc[mt][nt][1]);
          pk[2] = f2bf(acc[mt][nt][2]); pk[3] = f2bf(acc[mt][nt][3]);
          *(ushort4v*)(VT + (size_t)(bidx * H_ + h) * T_ + t0) = pk;
        }
      }
    }
  }
  gbar(gsync, 1024);

  // ========================= phase 2: flash attention ======================
  // Balanced causal pairing: block (b,jp,ch) does rows j1=jp and j2=31-jp,
  // tile set { t == ch (mod 8), t <= j } -> every block 4-5 tiles.
  {
    unsigned short* const Ksm  = (unsigned short*)smem;             // 2 x 8192
    unsigned short* const Vsm  = (unsigned short*)(smem + 32768);   // 2 x 8192
    unsigned short* const Plsm = (unsigned short*)(smem + 65536);   // 4 x 1152
    float* const Alsm = (float*)(smem + 65536 + 9216);              // 4 x 16

    const int b  = bid & 3;
    const int jp = (bid >> 2) & 15;
    const int ch = bid >> 6;         // 0..7
    const int j1 = jp, j2 = 31 - jp;
    const int n1 = (ch <= j1) ? (((j1 - ch) >> 3) + 1) : 0;
    const int n2 = ((j2 - ch) >> 3) + 1;   // >= 2 always
    const int ntt = n1 + n2;               // 4..5

    const unsigned short* Kb_b = Kb + (size_t)(b * T_) * H_;
    const unsigned short* VT_b = VT + (size_t)(b * H_) * T_;

    const int k_row4 = lane >> 4, k_slot = lane & 15;
    const int v_row8 = lane >> 3, v_slot = lane & 7;

#define STAGE_KV(buf, kv0_)                                                        \
    {                                                                              \
      _Pragma("unroll")                                                            \
      for (int i_ = 0; i_ < 4; ++i_) {                                             \
        const int r = wave * 16 + i_ * 4 + k_row4;                                 \
        const int c2 = (k_slot & 8) | ((k_slot ^ r) & 7);                          \
        gld16(Kb_b + (size_t)((kv0_) + r) * H_ + c2 * 8,                           \
              Ksm + (buf) * 8192 + (wave * 16 + i_ * 4) * 128);                    \
      }                                                                            \
      _Pragma("unroll")                                                            \
      for (int i_ = 0; i_ < 4; ++i_) {                                             \
        const int h = wave * 32 + i_ * 8 + v_row8;                                 \
        gld16(VT_b + (size_t)h * T_ + (kv0_) + ((v_slot ^ h) & 7) * 8,             \
              Vsm + (buf) * 8192 + (wave * 32 + i_ * 8) * 64);                     \
      }                                                                            \
    }

#define EPI(jr_)                                                                   \
    {                                                                              \
      const int pid = (b * 32 + (jr_)) * 8 + ch;                                   \
      unsigned short* po = Opart + (size_t)(pid * 64 + wave * 16) * H_;            \
      _Pragma("unroll")                                                            \
      for (int nth = 0; nth < 8; ++nth)                                            \
        _Pragma("unroll")                                                          \
        for (int r = 0; r < 4; ++r)                                                \
          po[(quad * 4 + r) * H_ + nth * 16 + l15] = f2bf(O[nth][r]);              \
      if (lane < 16) {                                                             \
        mpart[pid * 64 + wave * 16 + lane] = m_;                                   \
        lpart[pid * 64 + wave * 16 + lane] = l_;                                   \
      }                                                                            \
    }

    int jr_cur = n1 ? j1 : j2;
    short8 aq[4];
    {
      const unsigned short* qrow = Qb + (size_t)(b * T_ + jr_cur * 64 + wave * 16 + l15) * H_;
#pragma unroll
      for (int ks = 0; ks < 4; ++ks)
        aq[ks] = *(const short8*)(qrow + ks * 32 + quad * 8);
    }

    STAGE_KV(0, ch * 64);

    const f32x4 zero4 = {0.f, 0.f, 0.f, 0.f};
    f32x4 O[8];
#pragma unroll
    for (int nth = 0; nth < 8; ++nth) O[nth] = zero4;
    float m_ = NEG_BIG, l_ = 0.f;

    for (int i = 0; i < ntt; ++i) {
      __syncthreads();
      if (i + 1 < ntt) {
        const int in_ = i + 1;
        const int tn = (in_ < n1) ? (ch + (in_ << 3)) : (ch + ((in_ - n1) << 3));
        STAGE_KV((in_) & 1, tn * 64);
      }
      if (n1 && i == n1) {
        EPI(j1);
        m_ = NEG_BIG; l_ = 0.f;
#pragma unroll
        for (int nth = 0; nth < 8; ++nth) O[nth] = zero4;
        jr_cur = j2;
        const unsigned short* qrow = Qb + (size_t)(b * T_ + j2 * 64 + wave * 16 + l15) * H_;
#pragma unroll
        for (int ks = 0; ks < 4; ++ks)
          aq[ks] = *(const short8*)(qrow + ks * 32 + quad * 8);
      }
      const int ti  = (i < n1) ? (ch + (i << 3)) : (ch + ((i - n1) << 3));
      const int kv0 = ti * 64;

      // ---- S^T = K . Q^T
      const unsigned short* kb = Ksm + (i & 1) * 8192;
      f32x4 ST[4];
      ST[0] = zero4; ST[1] = zero4; ST[2] = zero4; ST[3] = zero4;
#pragma unroll
      for (int ntl = 0; ntl < 4; ++ntl) {
        const int kvr = ntl * 16 + l15;
#pragma unroll
        for (int ks = 0; ks < 4; ++ks) {
          const int c = ks * 4 + quad;
          const int slot = (c & 8) | ((c ^ kvr) & 7);
          short8 kf = *(const short8*)(kb + kvr * 128 + slot * 8);
          ST[ntl] = __builtin_amdgcn_mfma_f32_16x16x32_bf16(kf, aq[ks], ST[ntl], 0, 0, 0);
        }
      }

      // ---- causal mask (diagonal tile only)
      if (ti == jr_cur) {
        const int ql = jr_cur * 64 + wave * 16 + l15;
#pragma unroll
        for (int ntl = 0; ntl < 4; ++ntl)
#pragma unroll
          for (int r = 0; r < 4; ++r) {
            const int kl = kv0 + ntl * 16 + quad * 4 + r;
            if (kl > ql) ST[ntl][r] = NEG_BIG;
          }
      }

      // ---- softmax (per lane q=l15)
      float vmax = ST[0][0];
#pragma unroll
      for (int ntl = 0; ntl < 4; ++ntl)
#pragma unroll
        for (int r = 0; r < 4; ++r) vmax = fmaxf(vmax, ST[ntl][r]);
      vmax = fmaxf(vmax, __shfl_xor(vmax, 16));
      vmax = fmaxf(vmax, __shfl_xor(vmax, 32));
      const float mn = fmaxf(m_, vmax);
      const float alpha = __builtin_amdgcn_exp2f(m_ - mn);
      m_ = mn;
      float s = 0.f;
#pragma unroll
      for (int ntl = 0; ntl < 4; ++ntl)
#pragma unroll
        for (int r = 0; r < 4; ++r) {
          const float p = __builtin_amdgcn_exp2f(ST[ntl][r] - mn);
          ST[ntl][r] = p;
          s += p;
        }
      s += __shfl_xor(s, 16);
      s += __shfl_xor(s, 32);
      l_ = l_ * alpha + s;

      // ---- P -> LDS ([q][kv] layout)
#pragma unroll
      for (int ntl = 0; ntl < 4; ++ntl) {
        ushort4v pk;
        pk[0] = f2bf(ST[ntl][0]); pk[1] = f2bf(ST[ntl][1]);
        pk[2] = f2bf(ST[ntl][2]); pk[3] = f2bf(ST[ntl][3]);
        *(ushort4v*)(Plsm + wave * 1152 + l15 * 72 + ntl * 16 + quad * 4) = pk;
      }

      // ---- O rescale by alpha
      if (lane < 16) Alsm[wave * 16 + lane] = alpha;
      if (!__all(alpha == 1.f)) {
        f32x4 al4 = *(const f32x4*)(Alsm + wave * 16 + quad * 4);
#pragma unroll
        for (int nth = 0; nth < 8; ++nth)
#pragma unroll
          for (int r = 0; r < 4; ++r) O[nth][r] *= al4[r];
      }

      // ---- O += P . V
      const unsigned short* vb = Vsm + (i & 1) * 8192;
      short8 ap0 = *(const short8*)(Plsm + wave * 1152 + l15 * 72 + quad * 8);
      short8 ap1 = *(const short8*)(Plsm + wave * 1152 + l15 * 72 + 32 + quad * 8);
#pragma unroll
      for (int nth = 0; nth < 8; ++nth) {
        const int h = nth * 16 + l15;
        short8 v0 = *(const short8*)(vb + h * 64 + ((quad ^ h) & 7) * 8);
        short8 v1 = *(const short8*)(vb + h * 64 + (((4 + quad) ^ h) & 7) * 8);
        O[nth] = __builtin_amdgcn_mfma_f32_16x16x32_bf16(ap0, v0, O[nth], 0, 0, 0);
        O[nth] = __builtin_amdgcn_mfma_f32_16x16x32_bf16(ap1, v1, O[nth], 0, 0, 0);
      }
    }
    EPI(j2);
#undef STAGE_KV
#undef EPI
  }
  gbar(gsync, 1536);

  // ========================= phase 3: combine ==============================
  // 512 blocks: b(4) x j(32) x qi(4); each block 16 q-rows x 128 h.
  {
    const int b = bid & 3;
    const int j = (bid >> 2) & 31;
    const int qi = bid >> 7;
    const int nch = min(j + 1, 8);
    const int q = (tid >> 4) + qi * 16;   // 0..63
    const int h0 = (tid & 15) * 8;
    const int pbase = (b * 32 + j) * 8;

    float m_fin = NEG_BIG;
    for (int ch = 0; ch < nch; ++ch)
      m_fin = fmaxf(m_fin, mpart[(pbase + ch) * 64 + q]);
    float lf = 0.f;
    float o[8];
#pragma unroll
    for (int c = 0; c < 8; ++c) o[c] = 0.f;
    for (int ch = 0; ch < nch; ++ch) {
      const int pid = pbase + ch;
      const float sc = __builtin_amdgcn_exp2f(mpart[pid * 64 + q] - m_fin);
      lf += sc * lpart[pid * 64 + q];
      ushort8v pv = *(const ushort8v*)(Opart + (size_t)(pid * 64 + q) * H_ + h0);
#pragma unroll
      for (int c = 0; c < 8; ++c) o[c] += sc * bf2f(pv[c]);
    }
    const float inv = 1.0f / lf;
    float* op = out + (size_t)(b * T_ + j * 64 + q) * H_ + h0;
    f32x4 v0 = {o[0] * inv, o[1] * inv, o[2] * inv, o[3] * inv};
    f32x4 v1 = {o[4] * inv, o[5] * inv, o[6] * inv, o[7] * inv};
    *(f32x4*)(op) = v0;
    *(f32x4*)(op + 4) = v1;
  }
}

// ---------------------------------------------------------------------------
extern "C" void kernel_launch(void* const* d_in, const int* in_sizes, int n_in,
                              void* d_out, int out_size, void* d_ws, size_t ws_size,
                              hipStream_t stream) {
  const float* x  = (const float*)d_in[0];
  const float* Wq = (const float*)d_in[1];
  const float* Wk = (const float*)d_in[2];
  const float* Wv = (const float*)d_in[3];
  float* out = (float*)d_out;

  char* ws = (char*)d_ws;
  unsigned short* WbT = (unsigned short*)(ws);              // [0, 768 KB)
  unsigned short* Qb  = (unsigned short*)(ws + 1048576);    // [1 MB, 3 MB)
  unsigned short* Kb  = (unsigned short*)(ws + 3145728);    // [3 MB, 5 MB)
  unsigned short* VT  = (unsigned short*)(ws + 5242880);    // [5 MB, 7 MB)
  unsigned short* Opart = (unsigned short*)(ws + 8388608);  // [8 MB, 24 MB)
  float* mpart = (float*)(ws + 25165824);                   // [24 MB, +256 KB)
  float* lpart = (float*)(ws + 25427968);                   // [24.25 MB, +256 KB)
  unsigned int* gsync = (unsigned int*)(ws + 33554432);     // [32 MB, +256 B)

  // zero the barrier counter each iteration (graph-capturable)
  hipMemsetAsync(gsync, 0, 256, stream);

  hipLaunchKernelGGL(fused_head, dim3(512), dim3(256), 0, stream,
                     x, Wq, Wk, Wv, WbT, Qb, Kb, VT, Opart, mpart, lpart,
                     gsync, out);
}

// Round 4
// 156.557 us; speedup vs baseline: 3.2964x; 3.2964x over previous
//
#include <hip/hip_runtime.h>
#include <stdint.h>

#define B_ 4
#define T_ 2048
#define C_ 1024
#define H_ 128
#define NEG_BIG -3.0e38f

typedef __attribute__((ext_vector_type(8))) short short8;
typedef __attribute__((ext_vector_type(4))) float f32x4;
typedef __attribute__((ext_vector_type(4))) unsigned short ushort4v;
typedef __attribute__((ext_vector_type(8))) unsigned short ushort8v;

// cheap bf16 cast: round-half-up, <=0.5 ULP (validated R6-R9: absmax unchanged)
__device__ __forceinline__ unsigned short f2bf(float f) {
  union { float f; unsigned u; } cv; cv.f = f;
  return (unsigned short)((cv.u + 0x8000u) >> 16);
}

__device__ __forceinline__ float bf2f(unsigned short s) {
  union { unsigned u; float f; } cv; cv.u = ((unsigned)s) << 16;
  return cv.f;
}

// async global->LDS, 16 bytes per lane. LDS dest = wave-uniform base + lane*16.
__device__ __forceinline__ void gld16(const void* g, void* l) {
  __builtin_amdgcn_global_load_lds(
      (const __attribute__((address_space(1))) unsigned int*)g,
      (__attribute__((address_space(3))) unsigned int*)l, 16, 0, 0);
}

// scale = C^-0.5 = 1/32; folded with log2(e) for exp2-domain softmax
#define CSCALE 0.045084220027780106f

// ---------------------------------------------------------------------------
// Kernel 1: prep_w — cast Wq|Wk|Wv (fp32 [1024][128]) to WbT bf16 [384][1024]
// (transposed so B-fragments are contiguous). Tiny: ~2.3 MB traffic.
// ---------------------------------------------------------------------------
__global__ __launch_bounds__(256) void prep_w(const float* __restrict__ Wq,
                                              const float* __restrict__ Wk,
                                              const float* __restrict__ Wv,
                                              unsigned short* __restrict__ WbT) {
  const int i = blockIdx.x * 256 + threadIdx.x;   // 0..98303
  const int linear = i * 4;
  const int j = linear >> 10;
  const int k0 = linear & 1023;
  const float* W = (j < 128) ? Wq : (j < 256) ? Wk : Wv;
  const int h = j & 127;
  ushort4v p;
  p[0] = f2bf(W[(k0 + 0) * 128 + h]);
  p[1] = f2bf(W[(k0 + 1) * 128 + h]);
  p[2] = f2bf(W[(k0 + 2) * 128 + h]);
  p[3] = f2bf(W[(k0 + 3) * 128 + h]);
  *(ushort4v*)(WbT + linear) = p;
}

// ---------------------------------------------------------------------------
// Kernel 2: fused x-cast + QKV projection (R10 version, unchanged).
// 64M x 96N x 64K tiles, grid = 128 rb x 4 cb = 512 blocks -> 2 blocks/CU.
// rb = bid&127, cb = bid>>7: x-sharing siblings on same XCD.
// ---------------------------------------------------------------------------
__global__ __launch_bounds__(256, 2) void qkv_proj(const float* __restrict__ x,
                                                   const unsigned short* __restrict__ WbT,
                                                   unsigned short* __restrict__ Qb,
                                                   unsigned short* __restrict__ Kb,
                                                   unsigned short* __restrict__ VT) {
  __shared__ unsigned short As[2][64 * 64];   // 8 KB each
  __shared__ unsigned short Bs[2][96 * 64];   // 12 KB each

  const int tid  = threadIdx.x;
  const int wave = tid >> 6, lane = tid & 63;
  const int quad = lane >> 4, l15 = lane & 15;
  const int rb = blockIdx.x & 127, cb = blockIdx.x >> 7;  // siblings same XCD
  const int gm0 = rb * 64, gn0 = cb * 96;
  const int wm = wave >> 1, wn = wave & 1;

  const int srow = lane >> 3, sslot = lane & 7;   // B staging: 8 rows x 8 slots
  const int axr = tid >> 3, axc = tid & 7;        // 32 rows x 8 chunks
  const float* gAx = x + (size_t)(gm0 + axr) * C_ + axc * 8;

  // fragment read offsets (shorts)
  int aoff[2][2], boff[3][2];
#pragma unroll
  for (int mt = 0; mt < 2; ++mt) {
    const int r = wm * 32 + mt * 16 + l15;
#pragma unroll
    for (int ks = 0; ks < 2; ++ks)
      aoff[mt][ks] = r * 64 + (((ks * 4 + quad) ^ r) & 7) * 8;
  }
#pragma unroll
  for (int nt = 0; nt < 3; ++nt) {
    const int r = wn * 48 + nt * 16 + l15;
#pragma unroll
    for (int ks = 0; ks < 2; ++ks)
      boff[nt][ks] = r * 64 + (((ks * 4 + quad) ^ r) & 7) * 8;
  }

  f32x4 acc[2][3];
  const f32x4 zero4 = {0.f, 0.f, 0.f, 0.f};
#pragma unroll
  for (int mt = 0; mt < 2; ++mt)
#pragma unroll
    for (int nt = 0; nt < 3; ++nt) acc[mt][nt] = zero4;

#define STAGE_B(buf, kb_)                                                          \
  {                                                                                \
    const int ko = (kb_) * 64;                                                     \
    _Pragma("unroll")                                                              \
    for (int q = 0; q < 3; ++q) {                                                  \
      const int row = wave * 24 + q * 8 + srow;                                    \
      gld16(WbT + (size_t)(gn0 + row) * C_ + ko + ((sslot ^ row) & 7) * 8,         \
            &Bs[buf][(wave * 24 + q * 8) * 64]);                                   \
    }                                                                              \
  }

#define LOAD_A(ko_)                                                                \
  _Pragma("unroll")                                                                \
  for (int q = 0; q < 2; ++q) {                                                    \
    av0[q] = *(const f32x4*)(gAx + (size_t)(q * 32) * C_ + (ko_));                 \
    av1[q] = *(const f32x4*)(gAx + (size_t)(q * 32) * C_ + (ko_) + 4);             \
  }

#define WRITE_A(buf)                                                               \
  _Pragma("unroll")                                                                \
  for (int q = 0; q < 2; ++q) {                                                    \
    const int row = axr + q * 32;                                                  \
    short8 aw;                                                                     \
    _Pragma("unroll")                                                              \
    for (int e = 0; e < 4; ++e) {                                                  \
      aw[e]     = (short)f2bf(av0[q][e]);                                          \
      aw[4 + e] = (short)f2bf(av1[q][e]);                                          \
    }                                                                              \
    *(short8*)(&As[buf][row * 64 + ((axc ^ row) & 7) * 8]) = aw;                   \
  }

  f32x4 av0[2], av1[2];
  LOAD_A(0);
  STAGE_B(0, 0);
  WRITE_A(0);

  for (int kb = 0; kb < 16; ++kb) {
    __syncthreads();               // buf[kb&1] staged; prior reads of other done
    const int cur = kb & 1, nxt = cur ^ 1;
    if (kb + 1 < 16) {             // issue next-tile loads right after barrier
      LOAD_A((kb + 1) * 64);
      STAGE_B(nxt, kb + 1);
    }
    const unsigned short* Ac = As[cur];
    const unsigned short* Bc = Bs[cur];
#pragma unroll
    for (int ks = 0; ks < 2; ++ks) {
      short8 b0 = *(const short8*)(Bc + boff[0][ks]);
      short8 b1 = *(const short8*)(Bc + boff[1][ks]);
      short8 b2 = *(const short8*)(Bc + boff[2][ks]);
#pragma unroll
      for (int mt = 0; mt < 2; ++mt) {
        short8 a = *(const short8*)(Ac + aoff[mt][ks]);
        acc[mt][0] = __builtin_amdgcn_mfma_f32_16x16x32_bf16(a, b0, acc[mt][0], 0, 0, 0);
        acc[mt][1] = __builtin_amdgcn_mfma_f32_16x16x32_bf16(a, b1, acc[mt][1], 0, 0, 0);
        acc[mt][2] = __builtin_amdgcn_mfma_f32_16x16x32_bf16(a, b2, acc[mt][2], 0, 0, 0);
      }
    }
    if (kb + 1 < 16) WRITE_A(nxt);  // cvt + write next A after MFMAs issued
  }
#undef STAGE_B
#undef LOAD_A
#undef WRITE_A

  // epilogue: D[row=quad*4+r][col=l15] per 16x16 tile
#pragma unroll
  for (int mt = 0; mt < 2; ++mt) {
    const int row0 = gm0 + wm * 32 + mt * 16 + quad * 4;
#pragma unroll
    for (int nt = 0; nt < 3; ++nt) {
      const int colbase = gn0 + wn * 48 + nt * 16;
      const int col = colbase + l15;
      if (colbase < 128) {          // Q (pre-scaled)
#pragma unroll
        for (int r = 0; r < 4; ++r)
          Qb[(size_t)(row0 + r) * H_ + col] = f2bf(acc[mt][nt][r] * CSCALE);
      } else if (colbase < 256) {   // K
#pragma unroll
        for (int r = 0; r < 4; ++r)
          Kb[(size_t)(row0 + r) * H_ + (col - 128)] = f2bf(acc[mt][nt][r]);
      } else {                      // V, transposed
        const int h = col - 256;
        const int bidx = row0 >> 11;
        const int t0 = row0 & 2047;
        ushort4v pk;
        pk[0] = f2bf(acc[mt][nt][0]); pk[1] = f2bf(acc[mt][nt][1]);
        pk[2] = f2bf(acc[mt][nt][2]); pk[3] = f2bf(acc[mt][nt][3]);
        *(ushort4v*)(VT + (size_t)(bidx * H_ + h) * T_ + t0) = pk;
      }
    }
  }
}

// ---------------------------------------------------------------------------
// Kernel 3: flash attention stage 1 — R13: NO K/V LDS staging.
// K and V are L2-resident (per-b K+V = 1 MB; b = bid&3 pins one b per XCD's
// round-robin slots -> each XCD's L2 holds exactly its b). MFMA fragments
// load DIRECTLY from global (16-segment x 64B wave transactions, L2 hits).
// Removes: per-tile __syncthreads + vmcnt drains, double buffers, gld16s,
// all K/V LDS bank conflicts (743K/dispatch in R3's profile). Waves are now
// fully independent. Balanced causal pairing (rows jp and 31-jp, tile stride
// 8) unchanged. LDS: per-wave P repack + alpha only (9.5 KB).
// ---------------------------------------------------------------------------
__global__ __launch_bounds__(256, 2) void attn1(const unsigned short* __restrict__ Qb,
                                                const unsigned short* __restrict__ Kb,
                                                const unsigned short* __restrict__ VT,
                                                unsigned short* __restrict__ Opart,
                                                float* __restrict__ mpart,
                                                float* __restrict__ lpart) {
  __shared__ unsigned short Pls[4][16 * 72];   // 9 KB, per-wave P, pad 72
  __shared__ float Als[4][16];

  const int bid = blockIdx.x;
  const int b  = bid & 3;          // one b per XCD slot -> K/V L2-resident
  const int jp = (bid >> 2) & 15;
  const int ch = bid >> 6;         // 0..7
  const int j1 = jp, j2 = 31 - jp;
  const int n1 = (ch <= j1) ? (((j1 - ch) >> 3) + 1) : 0;  // tiles for row j1
  const int n2 = ((j2 - ch) >> 3) + 1;                     // tiles for row j2 (>=2)
  const int ntt = n1 + n2;                                 // 4..5 always

  const int tid  = threadIdx.x;
  const int wave = tid >> 6, lane = tid & 63;
  const int quad = lane >> 4, l15 = lane & 15;

  const unsigned short* Kb_b = Kb + (size_t)(b * T_) * H_;
  const unsigned short* VT_b = VT + (size_t)(b * H_) * T_;

  // partial epilogue: un-normalized O (bf16) + m, l for row jr_
#define EPI(jr_)                                                                   \
  {                                                                                \
    const int pid = (b * 32 + (jr_)) * 8 + ch;                                     \
    unsigned short* po = Opart + (size_t)(pid * 64 + wave * 16) * H_;              \
    _Pragma("unroll")                                                              \
    for (int nth = 0; nth < 8; ++nth)                                              \
      _Pragma("unroll")                                                            \
      for (int r = 0; r < 4; ++r)                                                  \
        po[(quad * 4 + r) * H_ + nth * 16 + l15] = f2bf(O[nth][r]);                \
    if (lane < 16) {                                                               \
      mpart[pid * 64 + wave * 16 + lane] = m_;                                     \
      lpart[pid * 64 + wave * 16 + lane] = l_;                                     \
    }                                                                              \
  }

  // Q fragments for current row block
  int jr_cur = n1 ? j1 : j2;
  short8 aq[4];
  {
    const unsigned short* qrow = Qb + (size_t)(b * T_ + jr_cur * 64 + wave * 16 + l15) * H_;
#pragma unroll
    for (int ks = 0; ks < 4; ++ks)
      aq[ks] = *(const short8*)(qrow + ks * 32 + quad * 8);
  }

  const f32x4 zero4 = {0.f, 0.f, 0.f, 0.f};
  f32x4 O[8];
#pragma unroll
  for (int nth = 0; nth < 8; ++nth) O[nth] = zero4;
  float m_ = NEG_BIG, l_ = 0.f;

  for (int i = 0; i < ntt; ++i) {
    if (n1 && i == n1) {
      // finalize row j1, reset state, switch Q to row j2
      EPI(j1);
      m_ = NEG_BIG; l_ = 0.f;
#pragma unroll
      for (int nth = 0; nth < 8; ++nth) O[nth] = zero4;
      jr_cur = j2;
      const unsigned short* qrow = Qb + (size_t)(b * T_ + j2 * 64 + wave * 16 + l15) * H_;
#pragma unroll
      for (int ks = 0; ks < 4; ++ks)
        aq[ks] = *(const short8*)(qrow + ks * 32 + quad * 8);
    }
    const int ti  = (i < n1) ? (ch + (i << 3)) : (ch + ((i - n1) << 3));
    const int kv0 = ti * 64;

    // ---- S^T = K . Q^T  (K fragments direct from global / L2)
    f32x4 ST[4];
    ST[0] = zero4; ST[1] = zero4; ST[2] = zero4; ST[3] = zero4;
#pragma unroll
    for (int ntl = 0; ntl < 4; ++ntl) {
      const unsigned short* krow = Kb_b + (size_t)(kv0 + ntl * 16 + l15) * H_;
#pragma unroll
      for (int ks = 0; ks < 4; ++ks) {
        short8 kf = *(const short8*)(krow + (ks * 4 + quad) * 8);
        ST[ntl] = __builtin_amdgcn_mfma_f32_16x16x32_bf16(kf, aq[ks], ST[ntl], 0, 0, 0);
      }
    }

    // ---- causal mask (diagonal tile only)
    if (ti == jr_cur) {
      const int ql = jr_cur * 64 + wave * 16 + l15;
#pragma unroll
      for (int ntl = 0; ntl < 4; ++ntl)
#pragma unroll
        for (int r = 0; r < 4; ++r) {
          const int kl = kv0 + ntl * 16 + quad * 4 + r;
          if (kl > ql) ST[ntl][r] = NEG_BIG;
        }
    }

    // ---- softmax (per lane q=l15)
    float vmax = ST[0][0];
#pragma unroll
    for (int ntl = 0; ntl < 4; ++ntl)
#pragma unroll
      for (int r = 0; r < 4; ++r) vmax = fmaxf(vmax, ST[ntl][r]);
    vmax = fmaxf(vmax, __shfl_xor(vmax, 16));
    vmax = fmaxf(vmax, __shfl_xor(vmax, 32));
    const float mn = fmaxf(m_, vmax);
    const float alpha = __builtin_amdgcn_exp2f(m_ - mn);
    m_ = mn;
    float s = 0.f;
#pragma unroll
    for (int ntl = 0; ntl < 4; ++ntl)
#pragma unroll
      for (int r = 0; r < 4; ++r) {
        const float p = __builtin_amdgcn_exp2f(ST[ntl][r] - mn);
        ST[ntl][r] = p;
        s += p;
      }
    s += __shfl_xor(s, 16);
    s += __shfl_xor(s, 32);
    l_ = l_ * alpha + s;

    // ---- P -> LDS ([q][kv] layout; per-wave, no barrier needed)
#pragma unroll
    for (int ntl = 0; ntl < 4; ++ntl) {
      ushort4v pk;
      pk[0] = f2bf(ST[ntl][0]); pk[1] = f2bf(ST[ntl][1]);
      pk[2] = f2bf(ST[ntl][2]); pk[3] = f2bf(ST[ntl][3]);
      *(ushort4v*)(&Pls[wave][l15 * 72 + ntl * 16 + quad * 4]) = pk;
    }

    // ---- O rescale by alpha
    if (lane < 16) Als[wave][lane] = alpha;
    if (!__all(alpha == 1.f)) {
      f32x4 al4 = *(const f32x4*)&Als[wave][quad * 4];
#pragma unroll
      for (int nth = 0; nth < 8; ++nth)
#pragma unroll
        for (int r = 0; r < 4; ++r) O[nth][r] *= al4[r];
    }

    // ---- O += P . V  (V fragments direct from global / L2)
    short8 ap0 = *(const short8*)(&Pls[wave][l15 * 72 + quad * 8]);
    short8 ap1 = *(const short8*)(&Pls[wave][l15 * 72 + 32 + quad * 8]);
#pragma unroll
    for (int nth = 0; nth < 8; ++nth) {
      const int h = nth * 16 + l15;
      const unsigned short* vrow = VT_b + (size_t)h * T_ + kv0;
      short8 v0 = *(const short8*)(vrow + quad * 8);
      short8 v1 = *(const short8*)(vrow + 32 + quad * 8);
      O[nth] = __builtin_amdgcn_mfma_f32_16x16x32_bf16(ap0, v0, O[nth], 0, 0, 0);
      O[nth] = __builtin_amdgcn_mfma_f32_16x16x32_bf16(ap1, v1, O[nth], 0, 0, 0);
    }
  }
  EPI(j2);
#undef EPI
}

// ---------------------------------------------------------------------------
// Kernel 4: stage-2 combine for ALL rows. Grid = 4 b x 32 j = 128 blocks.
// Row j has contributors ch in [0, min(j+1,8)).
// ---------------------------------------------------------------------------
__global__ __launch_bounds__(256) void attn2(const unsigned short* __restrict__ Opart,
                                             const float* __restrict__ mpart,
                                             const float* __restrict__ lpart,
                                             float* __restrict__ out) {
  const int b = blockIdx.x & 3;
  const int j = blockIdx.x >> 2;      // 0..31
  const int nch = min(j + 1, 8);      // 1..8
  const int tid = threadIdx.x;
  const int qh = tid >> 4;            // 0..15
  const int h0 = (tid & 15) * 8;
  const int pbase = (b * 32 + j) * 8;

#pragma unroll
  for (int i = 0; i < 4; ++i) {
    const int q = qh + i * 16;        // 0..63
    float m_fin = NEG_BIG;
    for (int ch = 0; ch < nch; ++ch)
      m_fin = fmaxf(m_fin, mpart[(pbase + ch) * 64 + q]);
    float lf = 0.f;
    float o[8];
#pragma unroll
    for (int c = 0; c < 8; ++c) o[c] = 0.f;
    for (int ch = 0; ch < nch; ++ch) {
      const int pid = pbase + ch;
      const float sc = __builtin_amdgcn_exp2f(mpart[pid * 64 + q] - m_fin);
      lf += sc * lpart[pid * 64 + q];
      ushort8v pv = *(const ushort8v*)(Opart + (size_t)(pid * 64 + q) * H_ + h0);
#pragma unroll
      for (int c = 0; c < 8; ++c) o[c] += sc * bf2f(pv[c]);
    }
    const float inv = 1.0f / lf;
    float* op = out + (size_t)(b * T_ + j * 64 + q) * H_ + h0;
    f32x4 v0 = {o[0] * inv, o[1] * inv, o[2] * inv, o[3] * inv};
    f32x4 v1 = {o[4] * inv, o[5] * inv, o[6] * inv, o[7] * inv};
    *(f32x4*)(op) = v0;
    *(f32x4*)(op + 4) = v1;
  }
}

// ---------------------------------------------------------------------------
extern "C" void kernel_launch(void* const* d_in, const int* in_sizes, int n_in,
                              void* d_out, int out_size, void* d_ws, size_t ws_size,
                              hipStream_t stream) {
  const float* x  = (const float*)d_in[0];
  const float* Wq = (const float*)d_in[1];
  const float* Wk = (const float*)d_in[2];
  const float* Wv = (const float*)d_in[3];
  float* out = (float*)d_out;

  char* ws = (char*)d_ws;
  unsigned short* WbT = (unsigned short*)(ws);              // [0, 768 KB)
  unsigned short* Qb  = (unsigned short*)(ws + 1048576);    // [1 MB, 3 MB)
  unsigned short* Kb  = (unsigned short*)(ws + 3145728);    // [3 MB, 5 MB)
  unsigned short* VT  = (unsigned short*)(ws + 5242880);    // [5 MB, 7 MB)
  unsigned short* Opart = (unsigned short*)(ws + 8388608);  // [8 MB, 24 MB)
  float* mpart = (float*)(ws + 25165824);                   // [24 MB, +256 KB)
  float* lpart = (float*)(ws + 25427968);                   // [24.25 MB, +256 KB)

  prep_w<<<dim3(384), dim3(256), 0, stream>>>(Wq, Wk, Wv, WbT);
  qkv_proj<<<dim3(512), dim3(256), 0, stream>>>(x, WbT, Qb, Kb, VT);
  attn1<<<dim3(512), dim3(256), 0, stream>>>(Qb, Kb, VT, Opart, mpart, lpart);
  attn2<<<dim3(128), dim3(256), 0, stream>>>(Opart, mpart, lpart, out);
}

// Round 7
// 121.054 us; speedup vs baseline: 4.2632x; 1.2933x over previous
//
#include <hip/hip_runtime.h>
#include <stdint.h>

#define B_ 4
#define T_ 2048
#define C_ 1024
#define H_ 128
#define NEG_BIG -3.0e38f

typedef __attribute__((ext_vector_type(8))) short short8;
typedef __attribute__((ext_vector_type(4))) float f32x4;
typedef __attribute__((ext_vector_type(4))) unsigned short ushort4v;
typedef __attribute__((ext_vector_type(8))) unsigned short ushort8v;

// cheap bf16 cast: round-half-up, <=0.5 ULP (validated R6-R9: absmax unchanged)
__device__ __forceinline__ unsigned short f2bf(float f) {
  union { float f; unsigned u; } cv; cv.f = f;
  return (unsigned short)((cv.u + 0x8000u) >> 16);
}

__device__ __forceinline__ float bf2f(unsigned short s) {
  union { unsigned u; float f; } cv; cv.u = ((unsigned)s) << 16;
  return cv.f;
}

// async global->LDS, 16 bytes per lane. LDS dest = wave-uniform base + lane*16.
__device__ __forceinline__ void gld16(const void* g, void* l) {
  __builtin_amdgcn_global_load_lds(
      (const __attribute__((address_space(1))) unsigned int*)g,
      (__attribute__((address_space(3))) unsigned int*)l, 16, 0, 0);
}

// scale = C^-0.5 = 1/32; folded with log2(e) for exp2-domain softmax
#define CSCALE 0.045084220027780106f

// ---------------------------------------------------------------------------
// Kernel 1: prep_w — cast Wq|Wk|Wv (fp32 [1024][128]) to WbT bf16 [384][1024]
// (transposed so B-fragments are contiguous). Tiny: ~2.3 MB traffic.
// ---------------------------------------------------------------------------
__global__ __launch_bounds__(256) void prep_w(const float* __restrict__ Wq,
                                              const float* __restrict__ Wk,
                                              const float* __restrict__ Wv,
                                              unsigned short* __restrict__ WbT) {
  const int i = blockIdx.x * 256 + threadIdx.x;   // 0..98303
  const int linear = i * 4;
  const int j = linear >> 10;
  const int k0 = linear & 1023;
  const float* W = (j < 128) ? Wq : (j < 256) ? Wk : Wv;
  const int h = j & 127;
  ushort4v p;
  p[0] = f2bf(W[(k0 + 0) * 128 + h]);
  p[1] = f2bf(W[(k0 + 1) * 128 + h]);
  p[2] = f2bf(W[(k0 + 2) * 128 + h]);
  p[3] = f2bf(W[(k0 + 3) * 128 + h]);
  *(ushort4v*)(WbT + linear) = p;
}

// ---------------------------------------------------------------------------
// Kernel 2: fused x-cast + QKV projection (R1 version, unchanged — proven).
// 64M x 96N x 64K tiles, grid = 128 rb x 4 cb = 512 blocks -> 2 blocks/CU.
// rb = bid&127, cb = bid>>7: x-sharing siblings on same XCD.
// ---------------------------------------------------------------------------
__global__ __launch_bounds__(256, 2) void qkv_proj(const float* __restrict__ x,
                                                   const unsigned short* __restrict__ WbT,
                                                   unsigned short* __restrict__ Qb,
                                                   unsigned short* __restrict__ Kb,
                                                   unsigned short* __restrict__ VT) {
  __shared__ unsigned short As[2][64 * 64];   // 8 KB each
  __shared__ unsigned short Bs[2][96 * 64];   // 12 KB each

  const int tid  = threadIdx.x;
  const int wave = tid >> 6, lane = tid & 63;
  const int quad = lane >> 4, l15 = lane & 15;
  const int rb = blockIdx.x & 127, cb = blockIdx.x >> 7;  // siblings same XCD
  const int gm0 = rb * 64, gn0 = cb * 96;
  const int wm = wave >> 1, wn = wave & 1;

  const int srow = lane >> 3, sslot = lane & 7;   // B staging: 8 rows x 8 slots
  const int axr = tid >> 3, axc = tid & 7;        // 32 rows x 8 chunks
  const float* gAx = x + (size_t)(gm0 + axr) * C_ + axc * 8;

  // fragment read offsets (shorts)
  int aoff[2][2], boff[3][2];
#pragma unroll
  for (int mt = 0; mt < 2; ++mt) {
    const int r = wm * 32 + mt * 16 + l15;
#pragma unroll
    for (int ks = 0; ks < 2; ++ks)
      aoff[mt][ks] = r * 64 + (((ks * 4 + quad) ^ r) & 7) * 8;
  }
#pragma unroll
  for (int nt = 0; nt < 3; ++nt) {
    const int r = wn * 48 + nt * 16 + l15;
#pragma unroll
    for (int ks = 0; ks < 2; ++ks)
      boff[nt][ks] = r * 64 + (((ks * 4 + quad) ^ r) & 7) * 8;
  }

  f32x4 acc[2][3];
  const f32x4 zero4 = {0.f, 0.f, 0.f, 0.f};
#pragma unroll
  for (int mt = 0; mt < 2; ++mt)
#pragma unroll
    for (int nt = 0; nt < 3; ++nt) acc[mt][nt] = zero4;

#define STAGE_B(buf, kb_)                                                          \
  {                                                                                \
    const int ko = (kb_) * 64;                                                     \
    _Pragma("unroll")                                                              \
    for (int q = 0; q < 3; ++q) {                                                  \
      const int row = wave * 24 + q * 8 + srow;                                    \
      gld16(WbT + (size_t)(gn0 + row) * C_ + ko + ((sslot ^ row) & 7) * 8,         \
            &Bs[buf][(wave * 24 + q * 8) * 64]);                                   \
    }                                                                              \
  }

#define LOAD_A(ko_)                                                                \
  _Pragma("unroll")                                                                \
  for (int q = 0; q < 2; ++q) {                                                    \
    av0[q] = *(const f32x4*)(gAx + (size_t)(q * 32) * C_ + (ko_));                 \
    av1[q] = *(const f32x4*)(gAx + (size_t)(q * 32) * C_ + (ko_) + 4);             \
  }

#define WRITE_A(buf)                                                               \
  _Pragma("unroll")                                                                \
  for (int q = 0; q < 2; ++q) {                                                    \
    const int row = axr + q * 32;                                                  \
    short8 aw;                                                                     \
    _Pragma("unroll")                                                              \
    for (int e = 0; e < 4; ++e) {                                                  \
      aw[e]     = (short)f2bf(av0[q][e]);                                          \
      aw[4 + e] = (short)f2bf(av1[q][e]);                                          \
    }                                                                              \
    *(short8*)(&As[buf][row * 64 + ((axc ^ row) & 7) * 8]) = aw;                   \
  }

  f32x4 av0[2], av1[2];
  LOAD_A(0);
  STAGE_B(0, 0);
  WRITE_A(0);

  for (int kb = 0; kb < 16; ++kb) {
    __syncthreads();               // buf[kb&1] staged; prior reads of other done
    const int cur = kb & 1, nxt = cur ^ 1;
    if (kb + 1 < 16) {             // issue next-tile loads right after barrier
      LOAD_A((kb + 1) * 64);
      STAGE_B(nxt, kb + 1);
    }
    const unsigned short* Ac = As[cur];
    const unsigned short* Bc = Bs[cur];
#pragma unroll
    for (int ks = 0; ks < 2; ++ks) {
      short8 b0 = *(const short8*)(Bc + boff[0][ks]);
      short8 b1 = *(const short8*)(Bc + boff[1][ks]);
      short8 b2 = *(const short8*)(Bc + boff[2][ks]);
#pragma unroll
      for (int mt = 0; mt < 2; ++mt) {
        short8 a = *(const short8*)(Ac + aoff[mt][ks]);
        acc[mt][0] = __builtin_amdgcn_mfma_f32_16x16x32_bf16(a, b0, acc[mt][0], 0, 0, 0);
        acc[mt][1] = __builtin_amdgcn_mfma_f32_16x16x32_bf16(a, b1, acc[mt][1], 0, 0, 0);
        acc[mt][2] = __builtin_amdgcn_mfma_f32_16x16x32_bf16(a, b2, acc[mt][2], 0, 0, 0);
      }
    }
    if (kb + 1 < 16) WRITE_A(nxt);  // cvt + write next A after MFMAs issued
  }
#undef STAGE_B
#undef LOAD_A
#undef WRITE_A

  // epilogue: D[row=quad*4+r][col=l15] per 16x16 tile
#pragma unroll
  for (int mt = 0; mt < 2; ++mt) {
    const int row0 = gm0 + wm * 32 + mt * 16 + quad * 4;
#pragma unroll
    for (int nt = 0; nt < 3; ++nt) {
      const int colbase = gn0 + wn * 48 + nt * 16;
      const int col = colbase + l15;
      if (colbase < 128) {          // Q (pre-scaled)
#pragma unroll
        for (int r = 0; r < 4; ++r)
          Qb[(size_t)(row0 + r) * H_ + col] = f2bf(acc[mt][nt][r] * CSCALE);
      } else if (colbase < 256) {   // K
#pragma unroll
        for (int r = 0; r < 4; ++r)
          Kb[(size_t)(row0 + r) * H_ + (col - 128)] = f2bf(acc[mt][nt][r]);
      } else {                      // V, transposed
        const int h = col - 256;
        const int bidx = row0 >> 11;
        const int t0 = row0 & 2047;
        ushort4v pk;
        pk[0] = f2bf(acc[mt][nt][0]); pk[1] = f2bf(acc[mt][nt][1]);
        pk[2] = f2bf(acc[mt][nt][2]); pk[3] = f2bf(acc[mt][nt][3]);
        *(ushort4v*)(VT + (size_t)(bidx * H_ + h) * T_ + t0) = pk;
      }
    }
  }
}

// ---------------------------------------------------------------------------
// Kernel 3: flash attention stage 1 (R1 body; atomics experiment abandoned —
// two container failures). Balanced causal pairing: block (b,jp,ch) does rows
// j1=jp and j2=31-jp, tile set { t == ch (mod 8), t <= j } -> 4-5 tiles/block.
// R7 tweak: alpha broadcast via __shfl (lane quad*4+r holds alpha for that
// q-row — all 4 lanes sharing l15 compute identical m_/alpha) instead of the
// Als LDS round-trip; removes an LDS write+read+lgkmcnt from the serial
// softmax->PV chain. No other changes.
// ---------------------------------------------------------------------------
__global__ __launch_bounds__(256, 2) void attn1(const unsigned short* __restrict__ Qb,
                                                const unsigned short* __restrict__ Kb,
                                                const unsigned short* __restrict__ VT,
                                                unsigned short* __restrict__ Opart,
                                                float* __restrict__ mpart,
                                                float* __restrict__ lpart) {
  __shared__ unsigned short Ks[2][64 * 128];   // 16 KB each; 16-slot rows
  __shared__ unsigned short Vs[2][128 * 64];   // 16 KB each; 8-slot rows
  __shared__ unsigned short Pls[4][16 * 72];   // 9 KB, per-wave P, pad 72

  const int bid = blockIdx.x;
  const int b  = bid & 3;
  const int jp = (bid >> 2) & 15;
  const int ch = bid >> 6;         // 0..7
  const int j1 = jp, j2 = 31 - jp;
  const int n1 = (ch <= j1) ? (((j1 - ch) >> 3) + 1) : 0;  // tiles for row j1
  const int n2 = ((j2 - ch) >> 3) + 1;                     // tiles for row j2 (>=2)
  const int ntt = n1 + n2;                                 // 4..5 always

  const int tid  = threadIdx.x;
  const int wave = tid >> 6, lane = tid & 63;
  const int quad = lane >> 4, l15 = lane & 15;

  const unsigned short* Kb_b = Kb + (size_t)(b * T_) * H_;
  const unsigned short* VT_b = VT + (size_t)(b * H_) * T_;

  const int k_row4 = lane >> 4, k_slot = lane & 15;
  const int v_row8 = lane >> 3, v_slot = lane & 7;

#define STAGE_KV(buf, kv0_)                                                        \
  {                                                                                \
    _Pragma("unroll")                                                              \
    for (int i_ = 0; i_ < 4; ++i_) {                                               \
      const int r = wave * 16 + i_ * 4 + k_row4;                                   \
      const int c2 = (k_slot & 8) | ((k_slot ^ r) & 7);                            \
      gld16(Kb_b + (size_t)((kv0_) + r) * H_ + c2 * 8,                             \
            &Ks[buf][(wave * 16 + i_ * 4) * 128]);                                 \
    }                                                                              \
    _Pragma("unroll")                                                              \
    for (int i_ = 0; i_ < 4; ++i_) {                                               \
      const int h = wave * 32 + i_ * 8 + v_row8;                                   \
      gld16(VT_b + (size_t)h * T_ + (kv0_) + ((v_slot ^ h) & 7) * 8,               \
            &Vs[buf][(wave * 32 + i_ * 8) * 64]);                                  \
    }                                                                              \
  }

  // partial epilogue: un-normalized O (bf16) + m, l for row jr_
#define EPI(jr_)                                                                   \
  {                                                                                \
    const int pid = (b * 32 + (jr_)) * 8 + ch;                                     \
    unsigned short* po = Opart + (size_t)(pid * 64 + wave * 16) * H_;              \
    _Pragma("unroll")                                                              \
    for (int nth = 0; nth < 8; ++nth)                                              \
      _Pragma("unroll")                                                            \
      for (int r = 0; r < 4; ++r)                                                  \
        po[(quad * 4 + r) * H_ + nth * 16 + l15] = f2bf(O[nth][r]);                \
    if (lane < 16) {                                                               \
      mpart[pid * 64 + wave * 16 + lane] = m_;                                     \
      lpart[pid * 64 + wave * 16 + lane] = l_;                                     \
    }                                                                              \
  }

  // Q fragments for current row block
  int jr_cur = n1 ? j1 : j2;
  short8 aq[4];
  {
    const unsigned short* qrow = Qb + (size_t)(b * T_ + jr_cur * 64 + wave * 16 + l15) * H_;
#pragma unroll
    for (int ks = 0; ks < 4; ++ks)
      aq[ks] = *(const short8*)(qrow + ks * 32 + quad * 8);
  }

  STAGE_KV(0, ch * 64);   // first tile is absolute tile index ch

  const f32x4 zero4 = {0.f, 0.f, 0.f, 0.f};
  f32x4 O[8];
#pragma unroll
  for (int nth = 0; nth < 8; ++nth) O[nth] = zero4;
  float m_ = NEG_BIG, l_ = 0.f;

  for (int i = 0; i < ntt; ++i) {
    __syncthreads();
    if (i + 1 < ntt) {
      const int in_ = i + 1;
      const int tn = (in_ < n1) ? (ch + (in_ << 3)) : (ch + ((in_ - n1) << 3));
      STAGE_KV((in_) & 1, tn * 64);
    }
    if (n1 && i == n1) {
      // finalize row j1, reset state, switch Q to row j2
      EPI(j1);
      m_ = NEG_BIG; l_ = 0.f;
#pragma unroll
      for (int nth = 0; nth < 8; ++nth) O[nth] = zero4;
      jr_cur = j2;
      const unsigned short* qrow = Qb + (size_t)(b * T_ + j2 * 64 + wave * 16 + l15) * H_;
#pragma unroll
      for (int ks = 0; ks < 4; ++ks)
        aq[ks] = *(const short8*)(qrow + ks * 32 + quad * 8);
    }
    const int ti  = (i < n1) ? (ch + (i << 3)) : (ch + ((i - n1) << 3));
    const int kv0 = ti * 64;

    // ---- S^T = K . Q^T
    const unsigned short* kb = Ks[i & 1];
    f32x4 ST[4];
    ST[0] = zero4; ST[1] = zero4; ST[2] = zero4; ST[3] = zero4;
#pragma unroll
    for (int ntl = 0; ntl < 4; ++ntl) {
      const int kvr = ntl * 16 + l15;
#pragma unroll
      for (int ks = 0; ks < 4; ++ks) {
        const int c = ks * 4 + quad;
        const int slot = (c & 8) | ((c ^ kvr) & 7);
        short8 kf = *(const short8*)(kb + kvr * 128 + slot * 8);
        ST[ntl] = __builtin_amdgcn_mfma_f32_16x16x32_bf16(kf, aq[ks], ST[ntl], 0, 0, 0);
      }
    }

    // ---- causal mask (diagonal tile only)
    if (ti == jr_cur) {
      const int ql = jr_cur * 64 + wave * 16 + l15;
#pragma unroll
      for (int ntl = 0; ntl < 4; ++ntl)
#pragma unroll
        for (int r = 0; r < 4; ++r) {
          const int kl = kv0 + ntl * 16 + quad * 4 + r;
          if (kl > ql) ST[ntl][r] = NEG_BIG;
        }
    }

    // ---- softmax (per lane q=l15)
    float vmax = ST[0][0];
#pragma unroll
    for (int ntl = 0; ntl < 4; ++ntl)
#pragma unroll
      for (int r = 0; r < 4; ++r) vmax = fmaxf(vmax, ST[ntl][r]);
    vmax = fmaxf(vmax, __shfl_xor(vmax, 16));
    vmax = fmaxf(vmax, __shfl_xor(vmax, 32));
    const float mn = fmaxf(m_, vmax);
    const float alpha = __builtin_amdgcn_exp2f(m_ - mn);
    m_ = mn;
    float s = 0.f;
#pragma unroll
    for (int ntl = 0; ntl < 4; ++ntl)
#pragma unroll
      for (int r = 0; r < 4; ++r) {
        const float p = __builtin_amdgcn_exp2f(ST[ntl][r] - mn);
        ST[ntl][r] = p;
        s += p;
      }
    s += __shfl_xor(s, 16);
    s += __shfl_xor(s, 32);
    l_ = l_ * alpha + s;

    // ---- P -> LDS ([q][kv] layout)
#pragma unroll
    for (int ntl = 0; ntl < 4; ++ntl) {
      ushort4v pk;
      pk[0] = f2bf(ST[ntl][0]); pk[1] = f2bf(ST[ntl][1]);
      pk[2] = f2bf(ST[ntl][2]); pk[3] = f2bf(ST[ntl][3]);
      *(ushort4v*)(&Pls[wave][l15 * 72 + ntl * 16 + quad * 4]) = pk;
    }

    // ---- O rescale by alpha (shfl broadcast: lane quad*4+r holds alpha of
    // q-row quad*4+r; no LDS round-trip)
    float alr[4];
#pragma unroll
    for (int r = 0; r < 4; ++r) alr[r] = __shfl(alpha, quad * 4 + r);
    if (!__all(alpha == 1.f)) {
#pragma unroll
      for (int nth = 0; nth < 8; ++nth)
#pragma unroll
        for (int r = 0; r < 4; ++r) O[nth][r] *= alr[r];
    }

    // ---- O += P . V
    const unsigned short* vb = Vs[i & 1];
    short8 ap0 = *(const short8*)(&Pls[wave][l15 * 72 + quad * 8]);
    short8 ap1 = *(const short8*)(&Pls[wave][l15 * 72 + 32 + quad * 8]);
#pragma unroll
    for (int nth = 0; nth < 8; ++nth) {
      const int h = nth * 16 + l15;
      short8 v0 = *(const short8*)(vb + h * 64 + ((quad ^ h) & 7) * 8);
      short8 v1 = *(const short8*)(vb + h * 64 + (((4 + quad) ^ h) & 7) * 8);
      O[nth] = __builtin_amdgcn_mfma_f32_16x16x32_bf16(ap0, v0, O[nth], 0, 0, 0);
      O[nth] = __builtin_amdgcn_mfma_f32_16x16x32_bf16(ap1, v1, O[nth], 0, 0, 0);
    }
  }
  EPI(j2);
#undef STAGE_KV
#undef EPI
}

// ---------------------------------------------------------------------------
// Kernel 4: stage-2 combine, spread over 512 blocks: b(4) x j(32) x qi(4);
// each block does 16 q-rows x 128 h (was 128 blocks x 64 rows — shorter tail).
// Row j has contributors ch in [0, min(j+1,8)).
// ---------------------------------------------------------------------------
__global__ __launch_bounds__(256) void attn2(const unsigned short* __restrict__ Opart,
                                             const float* __restrict__ mpart,
                                             const float* __restrict__ lpart,
                                             float* __restrict__ out) {
  const int b = blockIdx.x & 3;
  const int j = (blockIdx.x >> 2) & 31;
  const int qi = blockIdx.x >> 7;     // 0..3
  const int nch = min(j + 1, 8);      // 1..8
  const int tid = threadIdx.x;
  const int q = (tid >> 4) + qi * 16; // 0..63
  const int h0 = (tid & 15) * 8;
  const int pbase = (b * 32 + j) * 8;

  float m_fin = NEG_BIG;
  for (int ch = 0; ch < nch; ++ch)
    m_fin = fmaxf(m_fin, mpart[(pbase + ch) * 64 + q]);
  float lf = 0.f;
  float o[8];
#pragma unroll
  for (int c = 0; c < 8; ++c) o[c] = 0.f;
  for (int ch = 0; ch < nch; ++ch) {
    const int pid = pbase + ch;
    const float sc = __builtin_amdgcn_exp2f(mpart[pid * 64 + q] - m_fin);
    lf += sc * lpart[pid * 64 + q];
    ushort8v pv = *(const ushort8v*)(Opart + (size_t)(pid * 64 + q) * H_ + h0);
#pragma unroll
    for (int c = 0; c < 8; ++c) o[c] += sc * bf2f(pv[c]);
  }
  const float inv = 1.0f / lf;
  float* op = out + (size_t)(b * T_ + j * 64 + q) * H_ + h0;
  f32x4 v0 = {o[0] * inv, o[1] * inv, o[2] * inv, o[3] * inv};
  f32x4 v1 = {o[4] * inv, o[5] * inv, o[6] * inv, o[7] * inv};
  *(f32x4*)(op) = v0;
  *(f32x4*)(op + 4) = v1;
}

// ---------------------------------------------------------------------------
extern "C" void kernel_launch(void* const* d_in, const int* in_sizes, int n_in,
                              void* d_out, int out_size, void* d_ws, size_t ws_size,
                              hipStream_t stream) {
  const float* x  = (const float*)d_in[0];
  const float* Wq = (const float*)d_in[1];
  const float* Wk = (const float*)d_in[2];
  const float* Wv = (const float*)d_in[3];
  float* out = (float*)d_out;

  char* ws = (char*)d_ws;
  unsigned short* WbT = (unsigned short*)(ws);              // [0, 768 KB)
  unsigned short* Qb  = (unsigned short*)(ws + 1048576);    // [1 MB, 3 MB)
  unsigned short* Kb  = (unsigned short*)(ws + 3145728);    // [3 MB, 5 MB)
  unsigned short* VT  = (unsigned short*)(ws + 5242880);    // [5 MB, 7 MB)
  unsigned short* Opart = (unsigned short*)(ws + 8388608);  // [8 MB, 24 MB)
  float* mpart = (float*)(ws + 25165824);                   // [24 MB, +256 KB)
  float* lpart = (float*)(ws + 25427968);                   // [24.25 MB, +256 KB)

  prep_w<<<dim3(384), dim3(256), 0, stream>>>(Wq, Wk, Wv, WbT);
  qkv_proj<<<dim3(512), dim3(256), 0, stream>>>(x, WbT, Qb, Kb, VT);
  attn1<<<dim3(512), dim3(256), 0, stream>>>(Qb, Kb, VT, Opart, mpart, lpart);
  attn2<<<dim3(512), dim3(256), 0, stream>>>(Opart, mpart, lpart, out);
}

// Round 8
// 118.093 us; speedup vs baseline: 4.3701x; 1.0251x over previous
//
#include <hip/hip_runtime.h>
#include <stdint.h>

#define B_ 4
#define T_ 2048
#define C_ 1024
#define H_ 128
#define NEG_BIG -3.0e38f

typedef __attribute__((ext_vector_type(8))) short short8;
typedef __attribute__((ext_vector_type(4))) float f32x4;
typedef __attribute__((ext_vector_type(4))) unsigned short ushort4v;
typedef __attribute__((ext_vector_type(8))) unsigned short ushort8v;

// cheap bf16 cast: round-half-up, <=0.5 ULP (validated R6-R9: absmax unchanged)
__device__ __forceinline__ unsigned short f2bf(float f) {
  union { float f; unsigned u; } cv; cv.f = f;
  return (unsigned short)((cv.u + 0x8000u) >> 16);
}

__device__ __forceinline__ float bf2f(unsigned short s) {
  union { unsigned u; float f; } cv; cv.u = ((unsigned)s) << 16;
  return cv.f;
}

// async global->LDS, 16 bytes per lane. LDS dest = wave-uniform base + lane*16.
__device__ __forceinline__ void gld16(const void* g, void* l) {
  __builtin_amdgcn_global_load_lds(
      (const __attribute__((address_space(1))) unsigned int*)g,
      (__attribute__((address_space(3))) unsigned int*)l, 16, 0, 0);
}

// scale = C^-0.5 = 1/32; folded with log2(e) for exp2-domain softmax
#define CSCALE 0.045084220027780106f

// ---------------------------------------------------------------------------
// Kernel 1: prep_w — cast Wq|Wk|Wv (fp32 [1024][128]) to WbT bf16 [384][1024]
// (transposed so B-fragments are contiguous). Tiny: ~2.3 MB traffic.
// ---------------------------------------------------------------------------
__global__ __launch_bounds__(256) void prep_w(const float* __restrict__ Wq,
                                              const float* __restrict__ Wk,
                                              const float* __restrict__ Wv,
                                              unsigned short* __restrict__ WbT) {
  const int i = blockIdx.x * 256 + threadIdx.x;   // 0..98303
  const int linear = i * 4;
  const int j = linear >> 10;
  const int k0 = linear & 1023;
  const float* W = (j < 128) ? Wq : (j < 256) ? Wk : Wv;
  const int h = j & 127;
  ushort4v p;
  p[0] = f2bf(W[(k0 + 0) * 128 + h]);
  p[1] = f2bf(W[(k0 + 1) * 128 + h]);
  p[2] = f2bf(W[(k0 + 2) * 128 + h]);
  p[3] = f2bf(W[(k0 + 3) * 128 + h]);
  *(ushort4v*)(WbT + linear) = p;
}

// ---------------------------------------------------------------------------
// Kernel 2: fused x-cast + QKV projection.
// R8: 64M x 64N x 64K tiles, grid = 128 rb x 6 cb = 768 blocks ->
// 3 blocks/CU (was 2): the kernel is latency-bound (16 iters of gld16 drain +
// barrier at only 2 waves/SIMD); +50% TLP hides the x HBM stream.
// LDS 32 KB (As 16 + Bs 16). rb = bid&127, cb = bid>>7: all 6 x-sharing
// siblings on the same XCD (multiples of 128 are 0 mod 8). Wave 2x2 owns
// 32M x 32N (2 mt x 2 nt accs) -> 8 MFMA + 8 ds_read_b128 per iter.
// ---------------------------------------------------------------------------
__global__ __launch_bounds__(256, 3) void qkv_proj(const float* __restrict__ x,
                                                   const unsigned short* __restrict__ WbT,
                                                   unsigned short* __restrict__ Qb,
                                                   unsigned short* __restrict__ Kb,
                                                   unsigned short* __restrict__ VT) {
  __shared__ unsigned short As[2][64 * 64];   // 8 KB each
  __shared__ unsigned short Bs[2][64 * 64];   // 8 KB each

  const int tid  = threadIdx.x;
  const int wave = tid >> 6, lane = tid & 63;
  const int quad = lane >> 4, l15 = lane & 15;
  const int rb = blockIdx.x & 127, cb = blockIdx.x >> 7;  // siblings same XCD
  const int gm0 = rb * 64, gn0 = cb * 64;
  const int wm = wave >> 1, wn = wave & 1;

  const int srow = lane >> 3, sslot = lane & 7;   // B staging: 8 rows x 8 slots
  const int axr = tid >> 3, axc = tid & 7;        // 32 rows x 8 chunks
  const float* gAx = x + (size_t)(gm0 + axr) * C_ + axc * 8;

  // fragment read offsets (shorts)
  int aoff[2][2], boff[2][2];
#pragma unroll
  for (int mt = 0; mt < 2; ++mt) {
    const int r = wm * 32 + mt * 16 + l15;
#pragma unroll
    for (int ks = 0; ks < 2; ++ks)
      aoff[mt][ks] = r * 64 + (((ks * 4 + quad) ^ r) & 7) * 8;
  }
#pragma unroll
  for (int nt = 0; nt < 2; ++nt) {
    const int r = wn * 32 + nt * 16 + l15;
#pragma unroll
    for (int ks = 0; ks < 2; ++ks)
      boff[nt][ks] = r * 64 + (((ks * 4 + quad) ^ r) & 7) * 8;
  }

  f32x4 acc[2][2];
  const f32x4 zero4 = {0.f, 0.f, 0.f, 0.f};
#pragma unroll
  for (int mt = 0; mt < 2; ++mt)
#pragma unroll
    for (int nt = 0; nt < 2; ++nt) acc[mt][nt] = zero4;

#define STAGE_B(buf, kb_)                                                          \
  {                                                                                \
    const int ko = (kb_) * 64;                                                     \
    _Pragma("unroll")                                                              \
    for (int q = 0; q < 2; ++q) {                                                  \
      const int row = wave * 16 + q * 8 + srow;                                    \
      gld16(WbT + (size_t)(gn0 + row) * C_ + ko + ((sslot ^ row) & 7) * 8,         \
            &Bs[buf][(wave * 16 + q * 8) * 64]);                                   \
    }                                                                              \
  }

#define LOAD_A(ko_)                                                                \
  _Pragma("unroll")                                                                \
  for (int q = 0; q < 2; ++q) {                                                    \
    av0[q] = *(const f32x4*)(gAx + (size_t)(q * 32) * C_ + (ko_));                 \
    av1[q] = *(const f32x4*)(gAx + (size_t)(q * 32) * C_ + (ko_) + 4);             \
  }

#define WRITE_A(buf)                                                               \
  _Pragma("unroll")                                                                \
  for (int q = 0; q < 2; ++q) {                                                    \
    const int row = axr + q * 32;                                                  \
    short8 aw;                                                                     \
    _Pragma("unroll")                                                              \
    for (int e = 0; e < 4; ++e) {                                                  \
      aw[e]     = (short)f2bf(av0[q][e]);                                          \
      aw[4 + e] = (short)f2bf(av1[q][e]);                                          \
    }                                                                              \
    *(short8*)(&As[buf][row * 64 + ((axc ^ row) & 7) * 8]) = aw;                   \
  }

  f32x4 av0[2], av1[2];
  LOAD_A(0);
  STAGE_B(0, 0);
  WRITE_A(0);

  for (int kb = 0; kb < 16; ++kb) {
    __syncthreads();               // buf[kb&1] staged; prior reads of other done
    const int cur = kb & 1, nxt = cur ^ 1;
    if (kb + 1 < 16) {             // issue next-tile loads right after barrier
      LOAD_A((kb + 1) * 64);
      STAGE_B(nxt, kb + 1);
    }
    const unsigned short* Ac = As[cur];
    const unsigned short* Bc = Bs[cur];
#pragma unroll
    for (int ks = 0; ks < 2; ++ks) {
      short8 b0 = *(const short8*)(Bc + boff[0][ks]);
      short8 b1 = *(const short8*)(Bc + boff[1][ks]);
#pragma unroll
      for (int mt = 0; mt < 2; ++mt) {
        short8 a = *(const short8*)(Ac + aoff[mt][ks]);
        acc[mt][0] = __builtin_amdgcn_mfma_f32_16x16x32_bf16(a, b0, acc[mt][0], 0, 0, 0);
        acc[mt][1] = __builtin_amdgcn_mfma_f32_16x16x32_bf16(a, b1, acc[mt][1], 0, 0, 0);
      }
    }
    if (kb + 1 < 16) WRITE_A(nxt);  // cvt + write next A after MFMAs issued
  }
#undef STAGE_B
#undef LOAD_A
#undef WRITE_A

  // epilogue: D[row=quad*4+r][col=l15] per 16x16 tile
#pragma unroll
  for (int mt = 0; mt < 2; ++mt) {
    const int row0 = gm0 + wm * 32 + mt * 16 + quad * 4;
#pragma unroll
    for (int nt = 0; nt < 2; ++nt) {
      const int colbase = gn0 + wn * 32 + nt * 16;
      const int col = colbase + l15;
      if (colbase < 128) {          // Q (pre-scaled)
#pragma unroll
        for (int r = 0; r < 4; ++r)
          Qb[(size_t)(row0 + r) * H_ + col] = f2bf(acc[mt][nt][r] * CSCALE);
      } else if (colbase < 256) {   // K
#pragma unroll
        for (int r = 0; r < 4; ++r)
          Kb[(size_t)(row0 + r) * H_ + (col - 128)] = f2bf(acc[mt][nt][r]);
      } else {                      // V, transposed
        const int h = col - 256;
        const int bidx = row0 >> 11;
        const int t0 = row0 & 2047;
        ushort4v pk;
        pk[0] = f2bf(acc[mt][nt][0]); pk[1] = f2bf(acc[mt][nt][1]);
        pk[2] = f2bf(acc[mt][nt][2]); pk[3] = f2bf(acc[mt][nt][3]);
        *(ushort4v*)(VT + (size_t)(bidx * H_ + h) * T_ + t0) = pk;
      }
    }
  }
}

// ---------------------------------------------------------------------------
// Kernel 3: flash attention stage 1. R1 staged body + R7 shfl-alpha.
// R8: T13 defer-max (skip O-rescale + m-update when __all(pmax <= m_+8);
// P bounded by 2^8 — bf16 relative precision unchanged, combine math is
// invariant to the m-lag) and T5 s_setprio(1) around both MFMA clusters.
// Balanced causal pairing: rows j1=jp, j2=31-jp, tiles { t==ch mod 8 }.
// ---------------------------------------------------------------------------
__global__ __launch_bounds__(256, 2) void attn1(const unsigned short* __restrict__ Qb,
                                                const unsigned short* __restrict__ Kb,
                                                const unsigned short* __restrict__ VT,
                                                unsigned short* __restrict__ Opart,
                                                float* __restrict__ mpart,
                                                float* __restrict__ lpart) {
  __shared__ unsigned short Ks[2][64 * 128];   // 16 KB each; 16-slot rows
  __shared__ unsigned short Vs[2][128 * 64];   // 16 KB each; 8-slot rows
  __shared__ unsigned short Pls[4][16 * 72];   // 9 KB, per-wave P, pad 72

  const int bid = blockIdx.x;
  const int b  = bid & 3;
  const int jp = (bid >> 2) & 15;
  const int ch = bid >> 6;         // 0..7
  const int j1 = jp, j2 = 31 - jp;
  const int n1 = (ch <= j1) ? (((j1 - ch) >> 3) + 1) : 0;  // tiles for row j1
  const int n2 = ((j2 - ch) >> 3) + 1;                     // tiles for row j2 (>=2)
  const int ntt = n1 + n2;                                 // 4..5 always

  const int tid  = threadIdx.x;
  const int wave = tid >> 6, lane = tid & 63;
  const int quad = lane >> 4, l15 = lane & 15;

  const unsigned short* Kb_b = Kb + (size_t)(b * T_) * H_;
  const unsigned short* VT_b = VT + (size_t)(b * H_) * T_;

  const int k_row4 = lane >> 4, k_slot = lane & 15;
  const int v_row8 = lane >> 3, v_slot = lane & 7;

#define STAGE_KV(buf, kv0_)                                                        \
  {                                                                                \
    _Pragma("unroll")                                                              \
    for (int i_ = 0; i_ < 4; ++i_) {                                               \
      const int r = wave * 16 + i_ * 4 + k_row4;                                   \
      const int c2 = (k_slot & 8) | ((k_slot ^ r) & 7);                            \
      gld16(Kb_b + (size_t)((kv0_) + r) * H_ + c2 * 8,                             \
            &Ks[buf][(wave * 16 + i_ * 4) * 128]);                                 \
    }                                                                              \
    _Pragma("unroll")                                                              \
    for (int i_ = 0; i_ < 4; ++i_) {                                               \
      const int h = wave * 32 + i_ * 8 + v_row8;                                   \
      gld16(VT_b + (size_t)h * T_ + (kv0_) + ((v_slot ^ h) & 7) * 8,               \
            &Vs[buf][(wave * 32 + i_ * 8) * 64]);                                  \
    }                                                                              \
  }

  // partial epilogue: un-normalized O (bf16) + m, l for row jr_
#define EPI(jr_)                                                                   \
  {                                                                                \
    const int pid = (b * 32 + (jr_)) * 8 + ch;                                     \
    unsigned short* po = Opart + (size_t)(pid * 64 + wave * 16) * H_;              \
    _Pragma("unroll")                                                              \
    for (int nth = 0; nth < 8; ++nth)                                              \
      _Pragma("unroll")                                                            \
      for (int r = 0; r < 4; ++r)                                                  \
        po[(quad * 4 + r) * H_ + nth * 16 + l15] = f2bf(O[nth][r]);                \
    if (lane < 16) {                                                               \
      mpart[pid * 64 + wave * 16 + lane] = m_;                                     \
      lpart[pid * 64 + wave * 16 + lane] = l_;                                     \
    }                                                                              \
  }

  // Q fragments for current row block
  int jr_cur = n1 ? j1 : j2;
  short8 aq[4];
  {
    const unsigned short* qrow = Qb + (size_t)(b * T_ + jr_cur * 64 + wave * 16 + l15) * H_;
#pragma unroll
    for (int ks = 0; ks < 4; ++ks)
      aq[ks] = *(const short8*)(qrow + ks * 32 + quad * 8);
  }

  STAGE_KV(0, ch * 64);   // first tile is absolute tile index ch

  const f32x4 zero4 = {0.f, 0.f, 0.f, 0.f};
  f32x4 O[8];
#pragma unroll
  for (int nth = 0; nth < 8; ++nth) O[nth] = zero4;
  float m_ = NEG_BIG, l_ = 0.f;

  for (int i = 0; i < ntt; ++i) {
    __syncthreads();
    if (i + 1 < ntt) {
      const int in_ = i + 1;
      const int tn = (in_ < n1) ? (ch + (in_ << 3)) : (ch + ((in_ - n1) << 3));
      STAGE_KV((in_) & 1, tn * 64);
    }
    if (n1 && i == n1) {
      // finalize row j1, reset state, switch Q to row j2
      EPI(j1);
      m_ = NEG_BIG; l_ = 0.f;
#pragma unroll
      for (int nth = 0; nth < 8; ++nth) O[nth] = zero4;
      jr_cur = j2;
      const unsigned short* qrow = Qb + (size_t)(b * T_ + j2 * 64 + wave * 16 + l15) * H_;
#pragma unroll
      for (int ks = 0; ks < 4; ++ks)
        aq[ks] = *(const short8*)(qrow + ks * 32 + quad * 8);
    }
    const int ti  = (i < n1) ? (ch + (i << 3)) : (ch + ((i - n1) << 3));
    const int kv0 = ti * 64;

    // ---- S^T = K . Q^T
    const unsigned short* kb = Ks[i & 1];
    f32x4 ST[4];
    ST[0] = zero4; ST[1] = zero4; ST[2] = zero4; ST[3] = zero4;
    __builtin_amdgcn_s_setprio(1);
#pragma unroll
    for (int ntl = 0; ntl < 4; ++ntl) {
      const int kvr = ntl * 16 + l15;
#pragma unroll
      for (int ks = 0; ks < 4; ++ks) {
        const int c = ks * 4 + quad;
        const int slot = (c & 8) | ((c ^ kvr) & 7);
        short8 kf = *(const short8*)(kb + kvr * 128 + slot * 8);
        ST[ntl] = __builtin_amdgcn_mfma_f32_16x16x32_bf16(kf, aq[ks], ST[ntl], 0, 0, 0);
      }
    }
    __builtin_amdgcn_s_setprio(0);

    // ---- causal mask (diagonal tile only)
    if (ti == jr_cur) {
      const int ql = jr_cur * 64 + wave * 16 + l15;
#pragma unroll
      for (int ntl = 0; ntl < 4; ++ntl)
#pragma unroll
        for (int r = 0; r < 4; ++r) {
          const int kl = kv0 + ntl * 16 + quad * 4 + r;
          if (kl > ql) ST[ntl][r] = NEG_BIG;
        }
    }

    // ---- softmax (per lane q=l15), defer-max: only update m/rescale when
    // some row's max grew by > 8 (exp2 domain); else P <= 2^8, same rel. prec.
    float pmax = ST[0][0];
#pragma unroll
    for (int ntl = 0; ntl < 4; ++ntl)
#pragma unroll
      for (int r = 0; r < 4; ++r) pmax = fmaxf(pmax, ST[ntl][r]);
    pmax = fmaxf(pmax, __shfl_xor(pmax, 16));
    pmax = fmaxf(pmax, __shfl_xor(pmax, 32));
    if (!__all(pmax <= m_ + 8.f)) {
      const float mn = fmaxf(m_, pmax);
      const float alpha = __builtin_amdgcn_exp2f(m_ - mn);
      m_ = mn;
      l_ *= alpha;
      float alr[4];
#pragma unroll
      for (int r = 0; r < 4; ++r) alr[r] = __shfl(alpha, quad * 4 + r);
#pragma unroll
      for (int nth = 0; nth < 8; ++nth)
#pragma unroll
        for (int r = 0; r < 4; ++r) O[nth][r] *= alr[r];
    }
    float s = 0.f;
#pragma unroll
    for (int ntl = 0; ntl < 4; ++ntl)
#pragma unroll
      for (int r = 0; r < 4; ++r) {
        const float p = __builtin_amdgcn_exp2f(ST[ntl][r] - m_);
        ST[ntl][r] = p;
        s += p;
      }
    s += __shfl_xor(s, 16);
    s += __shfl_xor(s, 32);
    l_ += s;

    // ---- P -> LDS ([q][kv] layout)
#pragma unroll
    for (int ntl = 0; ntl < 4; ++ntl) {
      ushort4v pk;
      pk[0] = f2bf(ST[ntl][0]); pk[1] = f2bf(ST[ntl][1]);
      pk[2] = f2bf(ST[ntl][2]); pk[3] = f2bf(ST[ntl][3]);
      *(ushort4v*)(&Pls[wave][l15 * 72 + ntl * 16 + quad * 4]) = pk;
    }

    // ---- O += P . V
    const unsigned short* vb = Vs[i & 1];
    short8 ap0 = *(const short8*)(&Pls[wave][l15 * 72 + quad * 8]);
    short8 ap1 = *(const short8*)(&Pls[wave][l15 * 72 + 32 + quad * 8]);
    __builtin_amdgcn_s_setprio(1);
#pragma unroll
    for (int nth = 0; nth < 8; ++nth) {
      const int h = nth * 16 + l15;
      short8 v0 = *(const short8*)(vb + h * 64 + ((quad ^ h) & 7) * 8);
      short8 v1 = *(const short8*)(vb + h * 64 + (((4 + quad) ^ h) & 7) * 8);
      O[nth] = __builtin_amdgcn_mfma_f32_16x16x32_bf16(ap0, v0, O[nth], 0, 0, 0);
      O[nth] = __builtin_amdgcn_mfma_f32_16x16x32_bf16(ap1, v1, O[nth], 0, 0, 0);
    }
    __builtin_amdgcn_s_setprio(0);
  }
  EPI(j2);
#undef STAGE_KV
#undef EPI
}

// ---------------------------------------------------------------------------
// Kernel 4: stage-2 combine, 512 blocks: b(4) x j(32) x qi(4); each block
// 16 q-rows x 128 h. Row j has contributors ch in [0, min(j+1,8)).
// ---------------------------------------------------------------------------
__global__ __launch_bounds__(256) void attn2(const unsigned short* __restrict__ Opart,
                                             const float* __restrict__ mpart,
                                             const float* __restrict__ lpart,
                                             float* __restrict__ out) {
  const int b = blockIdx.x & 3;
  const int j = (blockIdx.x >> 2) & 31;
  const int qi = blockIdx.x >> 7;     // 0..3
  const int nch = min(j + 1, 8);      // 1..8
  const int tid = threadIdx.x;
  const int q = (tid >> 4) + qi * 16; // 0..63
  const int h0 = (tid & 15) * 8;
  const int pbase = (b * 32 + j) * 8;

  float m_fin = NEG_BIG;
  for (int ch = 0; ch < nch; ++ch)
    m_fin = fmaxf(m_fin, mpart[(pbase + ch) * 64 + q]);
  float lf = 0.f;
  float o[8];
#pragma unroll
  for (int c = 0; c < 8; ++c) o[c] = 0.f;
  for (int ch = 0; ch < nch; ++ch) {
    const int pid = pbase + ch;
    const float sc = __builtin_amdgcn_exp2f(mpart[pid * 64 + q] - m_fin);
    lf += sc * lpart[pid * 64 + q];
    ushort8v pv = *(const ushort8v*)(Opart + (size_t)(pid * 64 + q) * H_ + h0);
#pragma unroll
    for (int c = 0; c < 8; ++c) o[c] += sc * bf2f(pv[c]);
  }
  const float inv = 1.0f / lf;
  float* op = out + (size_t)(b * T_ + j * 64 + q) * H_ + h0;
  f32x4 v0 = {o[0] * inv, o[1] * inv, o[2] * inv, o[3] * inv};
  f32x4 v1 = {o[4] * inv, o[5] * inv, o[6] * inv, o[7] * inv};
  *(f32x4*)(op) = v0;
  *(f32x4*)(op + 4) = v1;
}

// ---------------------------------------------------------------------------
extern "C" void kernel_launch(void* const* d_in, const int* in_sizes, int n_in,
                              void* d_out, int out_size, void* d_ws, size_t ws_size,
                              hipStream_t stream) {
  const float* x  = (const float*)d_in[0];
  const float* Wq = (const float*)d_in[1];
  const float* Wk = (const float*)d_in[2];
  const float* Wv = (const float*)d_in[3];
  float* out = (float*)d_out;

  char* ws = (char*)d_ws;
  unsigned short* WbT = (unsigned short*)(ws);              // [0, 768 KB)
  unsigned short* Qb  = (unsigned short*)(ws + 1048576);    // [1 MB, 3 MB)
  unsigned short* Kb  = (unsigned short*)(ws + 3145728);    // [3 MB, 5 MB)
  unsigned short* VT  = (unsigned short*)(ws + 5242880);    // [5 MB, 7 MB)
  unsigned short* Opart = (unsigned short*)(ws + 8388608);  // [8 MB, 24 MB)
  float* mpart = (float*)(ws + 25165824);                   // [24 MB, +256 KB)
  float* lpart = (float*)(ws + 25427968);                   // [24.25 MB, +256 KB)

  prep_w<<<dim3(384), dim3(256), 0, stream>>>(Wq, Wk, Wv, WbT);
  qkv_proj<<<dim3(768), dim3(256), 0, stream>>>(x, WbT, Qb, Kb, VT);
  attn1<<<dim3(512), dim3(256), 0, stream>>>(Qb, Kb, VT, Opart, mpart, lpart);
  attn2<<<dim3(512), dim3(256), 0, stream>>>(Opart, mpart, lpart, out);
}

// Round 9
// 116.037 us; speedup vs baseline: 4.4476x; 1.0177x over previous
//
#include <hip/hip_runtime.h>
#include <stdint.h>

#define B_ 4
#define T_ 2048
#define C_ 1024
#define H_ 128
#define NEG_BIG -3.0e38f

typedef __attribute__((ext_vector_type(8))) short short8;
typedef __attribute__((ext_vector_type(4))) float f32x4;
typedef __attribute__((ext_vector_type(4))) unsigned short ushort4v;
typedef __attribute__((ext_vector_type(8))) unsigned short ushort8v;

// cheap bf16 cast: round-half-up, <=0.5 ULP (validated: absmax unchanged)
__device__ __forceinline__ unsigned short f2bf(float f) {
  union { float f; unsigned u; } cv; cv.f = f;
  return (unsigned short)((cv.u + 0x8000u) >> 16);
}

__device__ __forceinline__ float bf2f(unsigned short s) {
  union { unsigned u; float f; } cv; cv.u = ((unsigned)s) << 16;
  return cv.f;
}

// async global->LDS, 16 bytes per lane. LDS dest = wave-uniform base + lane*16.
__device__ __forceinline__ void gld16(const void* g, void* l) {
  __builtin_amdgcn_global_load_lds(
      (const __attribute__((address_space(1))) unsigned int*)g,
      (__attribute__((address_space(3))) unsigned int*)l, 16, 0, 0);
}

// scale = C^-0.5 = 1/32; folded with log2(e) for exp2-domain softmax
#define CSCALE 0.045084220027780106f

// ---------------------------------------------------------------------------
// Kernel 1 (R9): fused weight-cast + x-cast + QKV projection. prep_w kernel
// ELIMINATED: each block stages its B-tile directly from W fp32 with
// register-staging + in-register f2bf (values bit-identical to the old
// prep_w->WbT path). W is 1.5 MB -> L2-resident; the x128 redundant cast is
// ~5us of aggregate L2 reads, hidden under MFMA (T14 issue-early/write-late).
// 64M x 64N x 64K tiles, grid = 128 rb x 6 cb = 768 blocks -> 3 blocks/CU.
// rb = bid&127, cb = bid>>7: x-sharing siblings on same XCD. Each 64N tile
// lies in exactly one of Wq/Wk/Wv. B LDS swizzle slot = (c ^ r ^ (r>>3))&7:
// write-side (8 lanes per row-class -> 8 distinct slots) and read-side both
// bank-balanced; reads updated to match.
// ---------------------------------------------------------------------------
__global__ __launch_bounds__(256, 3) void qkv_proj(const float* __restrict__ x,
                                                   const float* __restrict__ Wq,
                                                   const float* __restrict__ Wk,
                                                   const float* __restrict__ Wv,
                                                   unsigned short* __restrict__ Qb,
                                                   unsigned short* __restrict__ Kb,
                                                   unsigned short* __restrict__ VT) {
  __shared__ unsigned short As[2][64 * 64];   // 8 KB each
  __shared__ unsigned short Bs[2][64 * 64];   // 8 KB each

  const int tid  = threadIdx.x;
  const int wave = tid >> 6, lane = tid & 63;
  const int quad = lane >> 4, l15 = lane & 15;
  const int rb = blockIdx.x & 127, cb = blockIdx.x >> 7;  // siblings same XCD
  const int gm0 = rb * 64, gn0 = cb * 64;
  const int wm = wave >> 1, wn = wave & 1;

  // B staging: thread -> (row bn = tid&63, k-chunk16 bkc = tid>>6)
  const int bn = tid & 63, bkc = tid >> 6;
  const float* Wsrc = (cb < 2) ? Wq : (cb < 4) ? Wk : Wv;
  const int bh = (gn0 & 127) + bn;            // column within Wsrc

  // A staging: thread -> (row = tid>>3 (+32q), chunk = tid&7)
  const int axr = tid >> 3, axc = tid & 7;    // 32 rows x 8 chunks
  const float* gAx = x + (size_t)(gm0 + axr) * C_ + axc * 8;

  // fragment read offsets (shorts)
  int aoff[2][2], boff[2][2];
#pragma unroll
  for (int mt = 0; mt < 2; ++mt) {
    const int r = wm * 32 + mt * 16 + l15;
#pragma unroll
    for (int ks = 0; ks < 2; ++ks)
      aoff[mt][ks] = r * 64 + (((ks * 4 + quad) ^ r) & 7) * 8;
  }
#pragma unroll
  for (int nt = 0; nt < 2; ++nt) {
    const int r = wn * 32 + nt * 16 + l15;
#pragma unroll
    for (int ks = 0; ks < 2; ++ks)
      boff[nt][ks] = r * 64 + ((((ks * 4 + quad)) ^ r ^ (r >> 3)) & 7) * 8;
  }

  f32x4 acc[2][2];
  const f32x4 zero4 = {0.f, 0.f, 0.f, 0.f};
#pragma unroll
  for (int mt = 0; mt < 2; ++mt)
#pragma unroll
    for (int nt = 0; nt < 2; ++nt) acc[mt][nt] = zero4;

  // B: load 16 fp32 (wave-coalesced 256B rows of W), cast later
#define LOAD_B(ko_)                                                                \
  _Pragma("unroll")                                                                \
  for (int kk = 0; kk < 16; ++kk)                                                  \
    bv[kk] = Wsrc[(size_t)((ko_) + bkc * 16 + kk) * 128 + bh];

#define WRITE_B(buf)                                                               \
  {                                                                                \
    short8 bw0, bw1;                                                               \
    _Pragma("unroll")                                                              \
    for (int e = 0; e < 8; ++e) {                                                  \
      bw0[e] = (short)f2bf(bv[e]);                                                 \
      bw1[e] = (short)f2bf(bv[8 + e]);                                             \
    }                                                                              \
    const int sx = bn ^ (bn >> 3);                                                 \
    *(short8*)(&Bs[buf][bn * 64 + (((bkc * 2) ^ sx) & 7) * 8]) = bw0;              \
    *(short8*)(&Bs[buf][bn * 64 + (((bkc * 2 + 1) ^ sx) & 7) * 8]) = bw1;          \
  }

#define LOAD_A(ko_)                                                                \
  _Pragma("unroll")                                                                \
  for (int q = 0; q < 2; ++q) {                                                    \
    av0[q] = *(const f32x4*)(gAx + (size_t)(q * 32) * C_ + (ko_));                 \
    av1[q] = *(const f32x4*)(gAx + (size_t)(q * 32) * C_ + (ko_) + 4);             \
  }

#define WRITE_A(buf)                                                               \
  _Pragma("unroll")                                                                \
  for (int q = 0; q < 2; ++q) {                                                    \
    const int row = axr + q * 32;                                                  \
    short8 aw;                                                                     \
    _Pragma("unroll")                                                              \
    for (int e = 0; e < 4; ++e) {                                                  \
      aw[e]     = (short)f2bf(av0[q][e]);                                          \
      aw[4 + e] = (short)f2bf(av1[q][e]);                                          \
    }                                                                              \
    *(short8*)(&As[buf][row * 64 + ((axc ^ row) & 7) * 8]) = aw;                   \
  }

  f32x4 av0[2], av1[2];
  float bv[16];
  LOAD_A(0);
  LOAD_B(0);
  WRITE_A(0);
  WRITE_B(0);

  for (int kb = 0; kb < 16; ++kb) {
    __syncthreads();               // buf[kb&1] staged; prior reads of other done
    const int cur = kb & 1, nxt = cur ^ 1;
    if (kb + 1 < 16) {             // issue next-tile loads right after barrier
      LOAD_A((kb + 1) * 64);
      LOAD_B((kb + 1) * 64);
    }
    const unsigned short* Ac = As[cur];
    const unsigned short* Bc = Bs[cur];
#pragma unroll
    for (int ks = 0; ks < 2; ++ks) {
      short8 b0 = *(const short8*)(Bc + boff[0][ks]);
      short8 b1 = *(const short8*)(Bc + boff[1][ks]);
#pragma unroll
      for (int mt = 0; mt < 2; ++mt) {
        short8 a = *(const short8*)(Ac + aoff[mt][ks]);
        acc[mt][0] = __builtin_amdgcn_mfma_f32_16x16x32_bf16(a, b0, acc[mt][0], 0, 0, 0);
        acc[mt][1] = __builtin_amdgcn_mfma_f32_16x16x32_bf16(a, b1, acc[mt][1], 0, 0, 0);
      }
    }
    if (kb + 1 < 16) {             // cvt + write next tile after MFMAs issued
      WRITE_A(nxt);
      WRITE_B(nxt);
    }
  }
#undef LOAD_B
#undef WRITE_B
#undef LOAD_A
#undef WRITE_A

  // epilogue: D[row=quad*4+r][col=l15] per 16x16 tile
#pragma unroll
  for (int mt = 0; mt < 2; ++mt) {
    const int row0 = gm0 + wm * 32 + mt * 16 + quad * 4;
#pragma unroll
    for (int nt = 0; nt < 2; ++nt) {
      const int colbase = gn0 + wn * 32 + nt * 16;
      const int col = colbase + l15;
      if (colbase < 128) {          // Q (pre-scaled)
#pragma unroll
        for (int r = 0; r < 4; ++r)
          Qb[(size_t)(row0 + r) * H_ + col] = f2bf(acc[mt][nt][r] * CSCALE);
      } else if (colbase < 256) {   // K
#pragma unroll
        for (int r = 0; r < 4; ++r)
          Kb[(size_t)(row0 + r) * H_ + (col - 128)] = f2bf(acc[mt][nt][r]);
      } else {                      // V, transposed
        const int h = col - 256;
        const int bidx = row0 >> 11;
        const int t0 = row0 & 2047;
        ushort4v pk;
        pk[0] = f2bf(acc[mt][nt][0]); pk[1] = f2bf(acc[mt][nt][1]);
        pk[2] = f2bf(acc[mt][nt][2]); pk[3] = f2bf(acc[mt][nt][3]);
        *(ushort4v*)(VT + (size_t)(bidx * H_ + h) * T_ + t0) = pk;
      }
    }
  }
}

// ---------------------------------------------------------------------------
// Kernel 2: flash attention stage 1 (R8 body, unchanged — passed at 118us).
// Balanced causal pairing: rows j1=jp, j2=31-jp, tiles { t==ch mod 8 }.
// T13 defer-max + T5 setprio around MFMA clusters; shfl-alpha broadcast.
// ---------------------------------------------------------------------------
__global__ __launch_bounds__(256, 2) void attn1(const unsigned short* __restrict__ Qb,
                                                const unsigned short* __restrict__ Kb,
                                                const unsigned short* __restrict__ VT,
                                                unsigned short* __restrict__ Opart,
                                                float* __restrict__ mpart,
                                                float* __restrict__ lpart) {
  __shared__ unsigned short Ks[2][64 * 128];   // 16 KB each; 16-slot rows
  __shared__ unsigned short Vs[2][128 * 64];   // 16 KB each; 8-slot rows
  __shared__ unsigned short Pls[4][16 * 72];   // 9 KB, per-wave P, pad 72

  const int bid = blockIdx.x;
  const int b  = bid & 3;
  const int jp = (bid >> 2) & 15;
  const int ch = bid >> 6;         // 0..7
  const int j1 = jp, j2 = 31 - jp;
  const int n1 = (ch <= j1) ? (((j1 - ch) >> 3) + 1) : 0;  // tiles for row j1
  const int n2 = ((j2 - ch) >> 3) + 1;                     // tiles for row j2 (>=2)
  const int ntt = n1 + n2;                                 // 4..5 always

  const int tid  = threadIdx.x;
  const int wave = tid >> 6, lane = tid & 63;
  const int quad = lane >> 4, l15 = lane & 15;

  const unsigned short* Kb_b = Kb + (size_t)(b * T_) * H_;
  const unsigned short* VT_b = VT + (size_t)(b * H_) * T_;

  const int k_row4 = lane >> 4, k_slot = lane & 15;
  const int v_row8 = lane >> 3, v_slot = lane & 7;

#define STAGE_KV(buf, kv0_)                                                        \
  {                                                                                \
    _Pragma("unroll")                                                              \
    for (int i_ = 0; i_ < 4; ++i_) {                                               \
      const int r = wave * 16 + i_ * 4 + k_row4;                                   \
      const int c2 = (k_slot & 8) | ((k_slot ^ r) & 7);                            \
      gld16(Kb_b + (size_t)((kv0_) + r) * H_ + c2 * 8,                             \
            &Ks[buf][(wave * 16 + i_ * 4) * 128]);                                 \
    }                                                                              \
    _Pragma("unroll")                                                              \
    for (int i_ = 0; i_ < 4; ++i_) {                                               \
      const int h = wave * 32 + i_ * 8 + v_row8;                                   \
      gld16(VT_b + (size_t)h * T_ + (kv0_) + ((v_slot ^ h) & 7) * 8,               \
            &Vs[buf][(wave * 32 + i_ * 8) * 64]);                                  \
    }                                                                              \
  }

  // partial epilogue: un-normalized O (bf16) + m, l for row jr_
#define EPI(jr_)                                                                   \
  {                                                                                \
    const int pid = (b * 32 + (jr_)) * 8 + ch;                                     \
    unsigned short* po = Opart + (size_t)(pid * 64 + wave * 16) * H_;              \
    _Pragma("unroll")                                                              \
    for (int nth = 0; nth < 8; ++nth)                                              \
      _Pragma("unroll")                                                            \
      for (int r = 0; r < 4; ++r)                                                  \
        po[(quad * 4 + r) * H_ + nth * 16 + l15] = f2bf(O[nth][r]);                \
    if (lane < 16) {                                                               \
      mpart[pid * 64 + wave * 16 + lane] = m_;                                     \
      lpart[pid * 64 + wave * 16 + lane] = l_;                                     \
    }                                                                              \
  }

  // Q fragments for current row block
  int jr_cur = n1 ? j1 : j2;
  short8 aq[4];
  {
    const unsigned short* qrow = Qb + (size_t)(b * T_ + jr_cur * 64 + wave * 16 + l15) * H_;
#pragma unroll
    for (int ks = 0; ks < 4; ++ks)
      aq[ks] = *(const short8*)(qrow + ks * 32 + quad * 8);
  }

  STAGE_KV(0, ch * 64);   // first tile is absolute tile index ch

  const f32x4 zero4 = {0.f, 0.f, 0.f, 0.f};
  f32x4 O[8];
#pragma unroll
  for (int nth = 0; nth < 8; ++nth) O[nth] = zero4;
  float m_ = NEG_BIG, l_ = 0.f;

  for (int i = 0; i < ntt; ++i) {
    __syncthreads();
    if (i + 1 < ntt) {
      const int in_ = i + 1;
      const int tn = (in_ < n1) ? (ch + (in_ << 3)) : (ch + ((in_ - n1) << 3));
      STAGE_KV((in_) & 1, tn * 64);
    }
    if (n1 && i == n1) {
      // finalize row j1, reset state, switch Q to row j2
      EPI(j1);
      m_ = NEG_BIG; l_ = 0.f;
#pragma unroll
      for (int nth = 0; nth < 8; ++nth) O[nth] = zero4;
      jr_cur = j2;
      const unsigned short* qrow = Qb + (size_t)(b * T_ + j2 * 64 + wave * 16 + l15) * H_;
#pragma unroll
      for (int ks = 0; ks < 4; ++ks)
        aq[ks] = *(const short8*)(qrow + ks * 32 + quad * 8);
    }
    const int ti  = (i < n1) ? (ch + (i << 3)) : (ch + ((i - n1) << 3));
    const int kv0 = ti * 64;

    // ---- S^T = K . Q^T
    const unsigned short* kb = Ks[i & 1];
    f32x4 ST[4];
    ST[0] = zero4; ST[1] = zero4; ST[2] = zero4; ST[3] = zero4;
    __builtin_amdgcn_s_setprio(1);
#pragma unroll
    for (int ntl = 0; ntl < 4; ++ntl) {
      const int kvr = ntl * 16 + l15;
#pragma unroll
      for (int ks = 0; ks < 4; ++ks) {
        const int c = ks * 4 + quad;
        const int slot = (c & 8) | ((c ^ kvr) & 7);
        short8 kf = *(const short8*)(kb + kvr * 128 + slot * 8);
        ST[ntl] = __builtin_amdgcn_mfma_f32_16x16x32_bf16(kf, aq[ks], ST[ntl], 0, 0, 0);
      }
    }
    __builtin_amdgcn_s_setprio(0);

    // ---- causal mask (diagonal tile only)
    if (ti == jr_cur) {
      const int ql = jr_cur * 64 + wave * 16 + l15;
#pragma unroll
      for (int ntl = 0; ntl < 4; ++ntl)
#pragma unroll
        for (int r = 0; r < 4; ++r) {
          const int kl = kv0 + ntl * 16 + quad * 4 + r;
          if (kl > ql) ST[ntl][r] = NEG_BIG;
        }
    }

    // ---- softmax (per lane q=l15), defer-max (T13)
    float pmax = ST[0][0];
#pragma unroll
    for (int ntl = 0; ntl < 4; ++ntl)
#pragma unroll
      for (int r = 0; r < 4; ++r) pmax = fmaxf(pmax, ST[ntl][r]);
    pmax = fmaxf(pmax, __shfl_xor(pmax, 16));
    pmax = fmaxf(pmax, __shfl_xor(pmax, 32));
    if (!__all(pmax <= m_ + 8.f)) {
      const float mn = fmaxf(m_, pmax);
      const float alpha = __builtin_amdgcn_exp2f(m_ - mn);
      m_ = mn;
      l_ *= alpha;
      float alr[4];
#pragma unroll
      for (int r = 0; r < 4; ++r) alr[r] = __shfl(alpha, quad * 4 + r);
#pragma unroll
      for (int nth = 0; nth < 8; ++nth)
#pragma unroll
        for (int r = 0; r < 4; ++r) O[nth][r] *= alr[r];
    }
    float s = 0.f;
#pragma unroll
    for (int ntl = 0; ntl < 4; ++ntl)
#pragma unroll
      for (int r = 0; r < 4; ++r) {
        const float p = __builtin_amdgcn_exp2f(ST[ntl][r] - m_);
        ST[ntl][r] = p;
        s += p;
      }
    s += __shfl_xor(s, 16);
    s += __shfl_xor(s, 32);
    l_ += s;

    // ---- P -> LDS ([q][kv] layout)
#pragma unroll
    for (int ntl = 0; ntl < 4; ++ntl) {
      ushort4v pk;
      pk[0] = f2bf(ST[ntl][0]); pk[1] = f2bf(ST[ntl][1]);
      pk[2] = f2bf(ST[ntl][2]); pk[3] = f2bf(ST[ntl][3]);
      *(ushort4v*)(&Pls[wave][l15 * 72 + ntl * 16 + quad * 4]) = pk;
    }

    // ---- O += P . V
    const unsigned short* vb = Vs[i & 1];
    short8 ap0 = *(const short8*)(&Pls[wave][l15 * 72 + quad * 8]);
    short8 ap1 = *(const short8*)(&Pls[wave][l15 * 72 + 32 + quad * 8]);
    __builtin_amdgcn_s_setprio(1);
#pragma unroll
    for (int nth = 0; nth < 8; ++nth) {
      const int h = nth * 16 + l15;
      short8 v0 = *(const short8*)(vb + h * 64 + ((quad ^ h) & 7) * 8);
      short8 v1 = *(const short8*)(vb + h * 64 + (((4 + quad) ^ h) & 7) * 8);
      O[nth] = __builtin_amdgcn_mfma_f32_16x16x32_bf16(ap0, v0, O[nth], 0, 0, 0);
      O[nth] = __builtin_amdgcn_mfma_f32_16x16x32_bf16(ap1, v1, O[nth], 0, 0, 0);
    }
    __builtin_amdgcn_s_setprio(0);
  }
  EPI(j2);
#undef STAGE_KV
#undef EPI
}

// ---------------------------------------------------------------------------
// Kernel 3: stage-2 combine, 512 blocks: b(4) x j(32) x qi(4); each block
// 16 q-rows x 128 h. Row j has contributors ch in [0, min(j+1,8)).
// ---------------------------------------------------------------------------
__global__ __launch_bounds__(256) void attn2(const unsigned short* __restrict__ Opart,
                                             const float* __restrict__ mpart,
                                             const float* __restrict__ lpart,
                                             float* __restrict__ out) {
  const int b = blockIdx.x & 3;
  const int j = (blockIdx.x >> 2) & 31;
  const int qi = blockIdx.x >> 7;     // 0..3
  const int nch = min(j + 1, 8);      // 1..8
  const int tid = threadIdx.x;
  const int q = (tid >> 4) + qi * 16; // 0..63
  const int h0 = (tid & 15) * 8;
  const int pbase = (b * 32 + j) * 8;

  float m_fin = NEG_BIG;
  for (int ch = 0; ch < nch; ++ch)
    m_fin = fmaxf(m_fin, mpart[(pbase + ch) * 64 + q]);
  float lf = 0.f;
  float o[8];
#pragma unroll
  for (int c = 0; c < 8; ++c) o[c] = 0.f;
  for (int ch = 0; ch < nch; ++ch) {
    const int pid = pbase + ch;
    const float sc = __builtin_amdgcn_exp2f(mpart[pid * 64 + q] - m_fin);
    lf += sc * lpart[pid * 64 + q];
    ushort8v pv = *(const ushort8v*)(Opart + (size_t)(pid * 64 + q) * H_ + h0);
#pragma unroll
    for (int c = 0; c < 8; ++c) o[c] += sc * bf2f(pv[c]);
  }
  const float inv = 1.0f / lf;
  float* op = out + (size_t)(b * T_ + j * 64 + q) * H_ + h0;
  f32x4 v0 = {o[0] * inv, o[1] * inv, o[2] * inv, o[3] * inv};
  f32x4 v1 = {o[4] * inv, o[5] * inv, o[6] * inv, o[7] * inv};
  *(f32x4*)(op) = v0;
  *(f32x4*)(op + 4) = v1;
}

// ---------------------------------------------------------------------------
extern "C" void kernel_launch(void* const* d_in, const int* in_sizes, int n_in,
                              void* d_out, int out_size, void* d_ws, size_t ws_size,
                              hipStream_t stream) {
  const float* x  = (const float*)d_in[0];
  const float* Wq = (const float*)d_in[1];
  const float* Wk = (const float*)d_in[2];
  const float* Wv = (const float*)d_in[3];
  float* out = (float*)d_out;

  char* ws = (char*)d_ws;
  unsigned short* Qb  = (unsigned short*)(ws + 1048576);    // [1 MB, 3 MB)
  unsigned short* Kb  = (unsigned short*)(ws + 3145728);    // [3 MB, 5 MB)
  unsigned short* VT  = (unsigned short*)(ws + 5242880);    // [5 MB, 7 MB)
  unsigned short* Opart = (unsigned short*)(ws + 8388608);  // [8 MB, 24 MB)
  float* mpart = (float*)(ws + 25165824);                   // [24 MB, +256 KB)
  float* lpart = (float*)(ws + 25427968);                   // [24.25 MB, +256 KB)

  qkv_proj<<<dim3(768), dim3(256), 0, stream>>>(x, Wq, Wk, Wv, Qb, Kb, VT);
  attn1<<<dim3(512), dim3(256), 0, stream>>>(Qb, Kb, VT, Opart, mpart, lpart);
  attn2<<<dim3(512), dim3(256), 0, stream>>>(Opart, mpart, lpart, out);
}

// Round 10
// 115.908 us; speedup vs baseline: 4.4525x; 1.0011x over previous
//
#include <hip/hip_runtime.h>
#include <stdint.h>

#define B_ 4
#define T_ 2048
#define C_ 1024
#define H_ 128
#define NEG_BIG -3.0e38f

typedef __attribute__((ext_vector_type(8))) short short8;
typedef __attribute__((ext_vector_type(4))) float f32x4;
typedef __attribute__((ext_vector_type(4))) unsigned short ushort4v;
typedef __attribute__((ext_vector_type(8))) unsigned short ushort8v;

// cheap bf16 cast: round-half-up, <=0.5 ULP (validated: absmax unchanged)
__device__ __forceinline__ unsigned short f2bf(float f) {
  union { float f; unsigned u; } cv; cv.f = f;
  return (unsigned short)((cv.u + 0x8000u) >> 16);
}

__device__ __forceinline__ float bf2f(unsigned short s) {
  union { unsigned u; float f; } cv; cv.u = ((unsigned)s) << 16;
  return cv.f;
}

// async global->LDS, 16 bytes per lane. LDS dest = wave-uniform base + lane*16.
__device__ __forceinline__ void gld16(const void* g, void* l) {
  __builtin_amdgcn_global_load_lds(
      (const __attribute__((address_space(1))) unsigned int*)g,
      (__attribute__((address_space(3))) unsigned int*)l, 16, 0, 0);
}

// scale = C^-0.5 = 1/32; folded with log2(e) for exp2-domain softmax
#define CSCALE 0.045084220027780106f

// ---------------------------------------------------------------------------
// Kernel 1: fused weight-cast + x-cast + QKV projection (R9 version, passed).
// 64M x 64N x 64K tiles, grid = 128 rb x 6 cb = 768 blocks -> 3 blocks/CU.
// B staged directly from W fp32 (reg + in-register f2bf, bit-identical).
// ---------------------------------------------------------------------------
__global__ __launch_bounds__(256, 3) void qkv_proj(const float* __restrict__ x,
                                                   const float* __restrict__ Wq,
                                                   const float* __restrict__ Wk,
                                                   const float* __restrict__ Wv,
                                                   unsigned short* __restrict__ Qb,
                                                   unsigned short* __restrict__ Kb,
                                                   unsigned short* __restrict__ VT) {
  __shared__ unsigned short As[2][64 * 64];   // 8 KB each
  __shared__ unsigned short Bs[2][64 * 64];   // 8 KB each

  const int tid  = threadIdx.x;
  const int wave = tid >> 6, lane = tid & 63;
  const int quad = lane >> 4, l15 = lane & 15;
  const int rb = blockIdx.x & 127, cb = blockIdx.x >> 7;  // siblings same XCD
  const int gm0 = rb * 64, gn0 = cb * 64;
  const int wm = wave >> 1, wn = wave & 1;

  // B staging: thread -> (row bn = tid&63, k-chunk16 bkc = tid>>6)
  const int bn = tid & 63, bkc = tid >> 6;
  const float* Wsrc = (cb < 2) ? Wq : (cb < 4) ? Wk : Wv;
  const int bh = (gn0 & 127) + bn;            // column within Wsrc

  // A staging: thread -> (row = tid>>3 (+32q), chunk = tid&7)
  const int axr = tid >> 3, axc = tid & 7;    // 32 rows x 8 chunks
  const float* gAx = x + (size_t)(gm0 + axr) * C_ + axc * 8;

  // fragment read offsets (shorts)
  int aoff[2][2], boff[2][2];
#pragma unroll
  for (int mt = 0; mt < 2; ++mt) {
    const int r = wm * 32 + mt * 16 + l15;
#pragma unroll
    for (int ks = 0; ks < 2; ++ks)
      aoff[mt][ks] = r * 64 + (((ks * 4 + quad) ^ r) & 7) * 8;
  }
#pragma unroll
  for (int nt = 0; nt < 2; ++nt) {
    const int r = wn * 32 + nt * 16 + l15;
#pragma unroll
    for (int ks = 0; ks < 2; ++ks)
      boff[nt][ks] = r * 64 + ((((ks * 4 + quad)) ^ r ^ (r >> 3)) & 7) * 8;
  }

  f32x4 acc[2][2];
  const f32x4 zero4 = {0.f, 0.f, 0.f, 0.f};
#pragma unroll
  for (int mt = 0; mt < 2; ++mt)
#pragma unroll
    for (int nt = 0; nt < 2; ++nt) acc[mt][nt] = zero4;

#define LOAD_B(ko_)                                                                \
  _Pragma("unroll")                                                                \
  for (int kk = 0; kk < 16; ++kk)                                                  \
    bv[kk] = Wsrc[(size_t)((ko_) + bkc * 16 + kk) * 128 + bh];

#define WRITE_B(buf)                                                               \
  {                                                                                \
    short8 bw0, bw1;                                                               \
    _Pragma("unroll")                                                              \
    for (int e = 0; e < 8; ++e) {                                                  \
      bw0[e] = (short)f2bf(bv[e]);                                                 \
      bw1[e] = (short)f2bf(bv[8 + e]);                                             \
    }                                                                              \
    const int sx = bn ^ (bn >> 3);                                                 \
    *(short8*)(&Bs[buf][bn * 64 + (((bkc * 2) ^ sx) & 7) * 8]) = bw0;              \
    *(short8*)(&Bs[buf][bn * 64 + (((bkc * 2 + 1) ^ sx) & 7) * 8]) = bw1;          \
  }

#define LOAD_A(ko_)                                                                \
  _Pragma("unroll")                                                                \
  for (int q = 0; q < 2; ++q) {                                                    \
    av0[q] = *(const f32x4*)(gAx + (size_t)(q * 32) * C_ + (ko_));                 \
    av1[q] = *(const f32x4*)(gAx + (size_t)(q * 32) * C_ + (ko_) + 4);             \
  }

#define WRITE_A(buf)                                                               \
  _Pragma("unroll")                                                                \
  for (int q = 0; q < 2; ++q) {                                                    \
    const int row = axr + q * 32;                                                  \
    short8 aw;                                                                     \
    _Pragma("unroll")                                                              \
    for (int e = 0; e < 4; ++e) {                                                  \
      aw[e]     = (short)f2bf(av0[q][e]);                                          \
      aw[4 + e] = (short)f2bf(av1[q][e]);                                          \
    }                                                                              \
    *(short8*)(&As[buf][row * 64 + ((axc ^ row) & 7) * 8]) = aw;                   \
  }

  f32x4 av0[2], av1[2];
  float bv[16];
  LOAD_A(0);
  LOAD_B(0);
  WRITE_A(0);
  WRITE_B(0);

  for (int kb = 0; kb < 16; ++kb) {
    __syncthreads();               // buf[kb&1] staged; prior reads of other done
    const int cur = kb & 1, nxt = cur ^ 1;
    if (kb + 1 < 16) {             // issue next-tile loads right after barrier
      LOAD_A((kb + 1) * 64);
      LOAD_B((kb + 1) * 64);
    }
    const unsigned short* Ac = As[cur];
    const unsigned short* Bc = Bs[cur];
#pragma unroll
    for (int ks = 0; ks < 2; ++ks) {
      short8 b0 = *(const short8*)(Bc + boff[0][ks]);
      short8 b1 = *(const short8*)(Bc + boff[1][ks]);
#pragma unroll
      for (int mt = 0; mt < 2; ++mt) {
        short8 a = *(const short8*)(Ac + aoff[mt][ks]);
        acc[mt][0] = __builtin_amdgcn_mfma_f32_16x16x32_bf16(a, b0, acc[mt][0], 0, 0, 0);
        acc[mt][1] = __builtin_amdgcn_mfma_f32_16x16x32_bf16(a, b1, acc[mt][1], 0, 0, 0);
      }
    }
    if (kb + 1 < 16) {             // cvt + write next tile after MFMAs issued
      WRITE_A(nxt);
      WRITE_B(nxt);
    }
  }
#undef LOAD_B
#undef WRITE_B
#undef LOAD_A
#undef WRITE_A

  // epilogue: D[row=quad*4+r][col=l15] per 16x16 tile
#pragma unroll
  for (int mt = 0; mt < 2; ++mt) {
    const int row0 = gm0 + wm * 32 + mt * 16 + quad * 4;
#pragma unroll
    for (int nt = 0; nt < 2; ++nt) {
      const int colbase = gn0 + wn * 32 + nt * 16;
      const int col = colbase + l15;
      if (colbase < 128) {          // Q (pre-scaled)
#pragma unroll
        for (int r = 0; r < 4; ++r)
          Qb[(size_t)(row0 + r) * H_ + col] = f2bf(acc[mt][nt][r] * CSCALE);
      } else if (colbase < 256) {   // K
#pragma unroll
        for (int r = 0; r < 4; ++r)
          Kb[(size_t)(row0 + r) * H_ + (col - 128)] = f2bf(acc[mt][nt][r]);
      } else {                      // V, transposed
        const int h = col - 256;
        const int bidx = row0 >> 11;
        const int t0 = row0 & 2047;
        ushort4v pk;
        pk[0] = f2bf(acc[mt][nt][0]); pk[1] = f2bf(acc[mt][nt][1]);
        pk[2] = f2bf(acc[mt][nt][2]); pk[3] = f2bf(acc[mt][nt][3]);
        *(ushort4v*)(VT + (size_t)(bidx * H_ + h) * T_ + t0) = pk;
      }
    }
  }
}

// ---------------------------------------------------------------------------
// Kernel 2: flash attention stage 1.
// R10: T14 staging restructure — single-buffered K/V LDS (41 KB total) with
// register staging (issue-early loads, write-late LDS stores) ->
// 3 blocks/CU (was 2 with 73 KB dbuf): +50% TLP for the latency-bound
// stage->QK->softmax->PV chain. Lane->address mapping identical to the old
// gld16 path (same swizzle, same LDS layout) so compute is untouched; absmax
// must stay exactly 0.0078125. 2 barriers/tile (read-done, write-visible).
// Balanced causal pairing + T13 defer-max + T5 setprio unchanged.
// ---------------------------------------------------------------------------
__global__ __launch_bounds__(256, 3) void attn1(const unsigned short* __restrict__ Qb,
                                                const unsigned short* __restrict__ Kb,
                                                const unsigned short* __restrict__ VT,
                                                unsigned short* __restrict__ Opart,
                                                float* __restrict__ mpart,
                                                float* __restrict__ lpart) {
  __shared__ unsigned short Ks[64 * 128];      // 16 KB; 16-slot rows
  __shared__ unsigned short Vs[128 * 64];      // 16 KB; 8-slot rows
  __shared__ unsigned short Pls[4][16 * 72];   // 9 KB, per-wave P, pad 72

  const int bid = blockIdx.x;
  const int b  = bid & 3;
  const int jp = (bid >> 2) & 15;
  const int ch = bid >> 6;         // 0..7
  const int j1 = jp, j2 = 31 - jp;
  const int n1 = (ch <= j1) ? (((j1 - ch) >> 3) + 1) : 0;  // tiles for row j1
  const int n2 = ((j2 - ch) >> 3) + 1;                     // tiles for row j2 (>=2)
  const int ntt = n1 + n2;                                 // 4..5 always

  const int tid  = threadIdx.x;
  const int wave = tid >> 6, lane = tid & 63;
  const int quad = lane >> 4, l15 = lane & 15;

  const unsigned short* Kb_b = Kb + (size_t)(b * T_) * H_;
  const unsigned short* VT_b = VT + (size_t)(b * H_) * T_;

  const int k_row4 = lane >> 4, k_slot = lane & 15;
  const int v_row8 = lane >> 3, v_slot = lane & 7;

  // register staging buffers (32 VGPRs)
  f32x4 kreg[4], vreg[4];

  // absolute kv tile index for loop position i_
#define TILE(i_) (((i_) < n1) ? (ch + ((i_) << 3)) : (ch + (((i_) - n1) << 3)))

  // issue global->reg loads for tile at kv0_ (same addresses as old gld16)
#define LOAD_KV(kv0_)                                                              \
  {                                                                                \
    _Pragma("unroll")                                                              \
    for (int i_ = 0; i_ < 4; ++i_) {                                               \
      const int r = wave * 16 + i_ * 4 + k_row4;                                   \
      const int c2 = (k_slot & 8) | ((k_slot ^ r) & 7);                            \
      kreg[i_] = *(const f32x4*)(Kb_b + (size_t)((kv0_) + r) * H_ + c2 * 8);       \
    }                                                                              \
    _Pragma("unroll")                                                              \
    for (int i_ = 0; i_ < 4; ++i_) {                                               \
      const int h = wave * 32 + i_ * 8 + v_row8;                                   \
      vreg[i_] = *(const f32x4*)(VT_b + (size_t)h * T_ + (kv0_) + ((v_slot ^ h) & 7) * 8); \
    }                                                                              \
  }

  // write staged regs -> LDS (same layout the gld16 path produced)
#define WRITE_KV()                                                                 \
  {                                                                                \
    _Pragma("unroll")                                                              \
    for (int i_ = 0; i_ < 4; ++i_) {                                               \
      const int r = wave * 16 + i_ * 4 + k_row4;                                   \
      *(f32x4*)(&Ks[r * 128 + k_slot * 8]) = kreg[i_];                             \
    }                                                                              \
    _Pragma("unroll")                                                              \
    for (int i_ = 0; i_ < 4; ++i_) {                                               \
      const int h = wave * 32 + i_ * 8 + v_row8;                                   \
      *(f32x4*)(&Vs[h * 64 + v_slot * 8]) = vreg[i_];                              \
    }                                                                              \
  }

  // partial epilogue: un-normalized O (bf16) + m, l for row jr_
#define EPI(jr_)                                                                   \
  {                                                                                \
    const int pid = (b * 32 + (jr_)) * 8 + ch;                                     \
    unsigned short* po = Opart + (size_t)(pid * 64 + wave * 16) * H_;              \
    _Pragma("unroll")                                                              \
    for (int nth = 0; nth < 8; ++nth)                                              \
      _Pragma("unroll")                                                            \
      for (int r = 0; r < 4; ++r)                                                  \
        po[(quad * 4 + r) * H_ + nth * 16 + l15] = f2bf(O[nth][r]);                \
    if (lane < 16) {                                                               \
      mpart[pid * 64 + wave * 16 + lane] = m_;                                     \
      lpart[pid * 64 + wave * 16 + lane] = l_;                                     \
    }                                                                              \
  }

  // Q fragments for current row block
  int jr_cur = n1 ? j1 : j2;
  short8 aq[4];
  {
    const unsigned short* qrow = Qb + (size_t)(b * T_ + jr_cur * 64 + wave * 16 + l15) * H_;
#pragma unroll
    for (int ks = 0; ks < 4; ++ks)
      aq[ks] = *(const short8*)(qrow + ks * 32 + quad * 8);
  }

  // prologue: stage tile 0, issue loads for tile 1
  LOAD_KV(TILE(0) * 64);
  WRITE_KV();
  LOAD_KV(TILE(1) * 64);   // ntt >= 2 always
  __syncthreads();

  const f32x4 zero4 = {0.f, 0.f, 0.f, 0.f};
  f32x4 O[8];
#pragma unroll
  for (int nth = 0; nth < 8; ++nth) O[nth] = zero4;
  float m_ = NEG_BIG, l_ = 0.f;

  for (int i = 0; i < ntt; ++i) {
    if (n1 && i == n1) {
      // finalize row j1, reset state, switch Q to row j2
      EPI(j1);
      m_ = NEG_BIG; l_ = 0.f;
#pragma unroll
      for (int nth = 0; nth < 8; ++nth) O[nth] = zero4;
      jr_cur = j2;
      const unsigned short* qrow = Qb + (size_t)(b * T_ + j2 * 64 + wave * 16 + l15) * H_;
#pragma unroll
      for (int ks = 0; ks < 4; ++ks)
        aq[ks] = *(const short8*)(qrow + ks * 32 + quad * 8);
    }
    const int ti  = TILE(i);
    const int kv0 = ti * 64;

    // ---- S^T = K . Q^T
    f32x4 ST[4];
    ST[0] = zero4; ST[1] = zero4; ST[2] = zero4; ST[3] = zero4;
    __builtin_amdgcn_s_setprio(1);
#pragma unroll
    for (int ntl = 0; ntl < 4; ++ntl) {
      const int kvr = ntl * 16 + l15;
#pragma unroll
      for (int ks = 0; ks < 4; ++ks) {
        const int c = ks * 4 + quad;
        const int slot = (c & 8) | ((c ^ kvr) & 7);
        short8 kf = *(const short8*)(Ks + kvr * 128 + slot * 8);
        ST[ntl] = __builtin_amdgcn_mfma_f32_16x16x32_bf16(kf, aq[ks], ST[ntl], 0, 0, 0);
      }
    }
    __builtin_amdgcn_s_setprio(0);

    // ---- causal mask (diagonal tile only)
    if (ti == jr_cur) {
      const int ql = jr_cur * 64 + wave * 16 + l15;
#pragma unroll
      for (int ntl = 0; ntl < 4; ++ntl)
#pragma unroll
        for (int r = 0; r < 4; ++r) {
          const int kl = kv0 + ntl * 16 + quad * 4 + r;
          if (kl > ql) ST[ntl][r] = NEG_BIG;
        }
    }

    // ---- softmax (per lane q=l15), defer-max (T13)
    float pmax = ST[0][0];
#pragma unroll
    for (int ntl = 0; ntl < 4; ++ntl)
#pragma unroll
      for (int r = 0; r < 4; ++r) pmax = fmaxf(pmax, ST[ntl][r]);
    pmax = fmaxf(pmax, __shfl_xor(pmax, 16));
    pmax = fmaxf(pmax, __shfl_xor(pmax, 32));
    if (!__all(pmax <= m_ + 8.f)) {
      const float mn = fmaxf(m_, pmax);
      const float alpha = __builtin_amdgcn_exp2f(m_ - mn);
      m_ = mn;
      l_ *= alpha;
      float alr[4];
#pragma unroll
      for (int r = 0; r < 4; ++r) alr[r] = __shfl(alpha, quad * 4 + r);
#pragma unroll
      for (int nth = 0; nth < 8; ++nth)
#pragma unroll
        for (int r = 0; r < 4; ++r) O[nth][r] *= alr[r];
    }
    float s = 0.f;
#pragma unroll
    for (int ntl = 0; ntl < 4; ++ntl)
#pragma unroll
      for (int r = 0; r < 4; ++r) {
        const float p = __builtin_amdgcn_exp2f(ST[ntl][r] - m_);
        ST[ntl][r] = p;
        s += p;
      }
    s += __shfl_xor(s, 16);
    s += __shfl_xor(s, 32);
    l_ += s;

    // ---- P -> LDS ([q][kv] layout; per-wave region, no barrier)
#pragma unroll
    for (int ntl = 0; ntl < 4; ++ntl) {
      ushort4v pk;
      pk[0] = f2bf(ST[ntl][0]); pk[1] = f2bf(ST[ntl][1]);
      pk[2] = f2bf(ST[ntl][2]); pk[3] = f2bf(ST[ntl][3]);
      *(ushort4v*)(&Pls[wave][l15 * 72 + ntl * 16 + quad * 4]) = pk;
    }

    // ---- O += P . V
    short8 ap0 = *(const short8*)(&Pls[wave][l15 * 72 + quad * 8]);
    short8 ap1 = *(const short8*)(&Pls[wave][l15 * 72 + 32 + quad * 8]);
    __builtin_amdgcn_s_setprio(1);
#pragma unroll
    for (int nth = 0; nth < 8; ++nth) {
      const int h = nth * 16 + l15;
      short8 v0 = *(const short8*)(Vs + h * 64 + ((quad ^ h) & 7) * 8);
      short8 v1 = *(const short8*)(Vs + h * 64 + (((4 + quad) ^ h) & 7) * 8);
      O[nth] = __builtin_amdgcn_mfma_f32_16x16x32_bf16(ap0, v0, O[nth], 0, 0, 0);
      O[nth] = __builtin_amdgcn_mfma_f32_16x16x32_bf16(ap1, v1, O[nth], 0, 0, 0);
    }
    __builtin_amdgcn_s_setprio(0);

    // ---- rotate staging: write tile i+1, issue loads for tile i+2
    if (i + 1 < ntt) {
      __syncthreads();             // all waves done reading Ks/Vs (tile i)
      WRITE_KV();                  // stage tile i+1 (regs loaded earlier)
      if (i + 2 < ntt) LOAD_KV(TILE(i + 2) * 64);
      __syncthreads();             // tile i+1 visible
    }
  }
  EPI(j2);
#undef TILE
#undef LOAD_KV
#undef WRITE_KV
#undef EPI
}

// ---------------------------------------------------------------------------
// Kernel 3: stage-2 combine, 512 blocks: b(4) x j(32) x qi(4); each block
// 16 q-rows x 128 h. Row j has contributors ch in [0, min(j+1,8)).
// ---------------------------------------------------------------------------
__global__ __launch_bounds__(256) void attn2(const unsigned short* __restrict__ Opart,
                                             const float* __restrict__ mpart,
                                             const float* __restrict__ lpart,
                                             float* __restrict__ out) {
  const int b = blockIdx.x & 3;
  const int j = (blockIdx.x >> 2) & 31;
  const int qi = blockIdx.x >> 7;     // 0..3
  const int nch = min(j + 1, 8);      // 1..8
  const int tid = threadIdx.x;
  const int q = (tid >> 4) + qi * 16; // 0..63
  const int h0 = (tid & 15) * 8;
  const int pbase = (b * 32 + j) * 8;

  float m_fin = NEG_BIG;
  for (int ch = 0; ch < nch; ++ch)
    m_fin = fmaxf(m_fin, mpart[(pbase + ch) * 64 + q]);
  float lf = 0.f;
  float o[8];
#pragma unroll
  for (int c = 0; c < 8; ++c) o[c] = 0.f;
  for (int ch = 0; ch < nch; ++ch) {
    const int pid = pbase + ch;
    const float sc = __builtin_amdgcn_exp2f(mpart[pid * 64 + q] - m_fin);
    lf += sc * lpart[pid * 64 + q];
    ushort8v pv = *(const ushort8v*)(Opart + (size_t)(pid * 64 + q) * H_ + h0);
#pragma unroll
    for (int c = 0; c < 8; ++c) o[c] += sc * bf2f(pv[c]);
  }
  const float inv = 1.0f / lf;
  float* op = out + (size_t)(b * T_ + j * 64 + q) * H_ + h0;
  f32x4 v0 = {o[0] * inv, o[1] * inv, o[2] * inv, o[3] * inv};
  f32x4 v1 = {o[4] * inv, o[5] * inv, o[6] * inv, o[7] * inv};
  *(f32x4*)(op) = v0;
  *(f32x4*)(op + 4) = v1;
}

// ---------------------------------------------------------------------------
extern "C" void kernel_launch(void* const* d_in, const int* in_sizes, int n_in,
                              void* d_out, int out_size, void* d_ws, size_t ws_size,
                              hipStream_t stream) {
  const float* x  = (const float*)d_in[0];
  const float* Wq = (const float*)d_in[1];
  const float* Wk = (const float*)d_in[2];
  const float* Wv = (const float*)d_in[3];
  float* out = (float*)d_out;

  char* ws = (char*)d_ws;
  unsigned short* Qb  = (unsigned short*)(ws + 1048576);    // [1 MB, 3 MB)
  unsigned short* Kb  = (unsigned short*)(ws + 3145728);    // [3 MB, 5 MB)
  unsigned short* VT  = (unsigned short*)(ws + 5242880);    // [5 MB, 7 MB)
  unsigned short* Opart = (unsigned short*)(ws + 8388608);  // [8 MB, 24 MB)
  float* mpart = (float*)(ws + 25165824);                   // [24 MB, +256 KB)
  float* lpart = (float*)(ws + 25427968);                   // [24.25 MB, +256 KB)

  qkv_proj<<<dim3(768), dim3(256), 0, stream>>>(x, Wq, Wk, Wv, Qb, Kb, VT);
  attn1<<<dim3(512), dim3(256), 0, stream>>>(Qb, Kb, VT, Opart, mpart, lpart);
  attn2<<<dim3(512), dim3(256), 0, stream>>>(Opart, mpart, lpart, out);
}